// Round 10
// baseline (4897.804 us; speedup 1.0000x reference)
//
#include <hip/hip_runtime.h>
#include <math.h>
#include <type_traits>

// Problem constants
#define NB 512     // batch
#define HD 512     // hidden
#define CD 64      // in channels
#define TD 168     // encode length
#define DSTEPS 24  // decoder steps
#define OUTC 64    // out channels
#define GATES 2048 // 4*HD
#define KWE (HD + CD)   // encoder K = 576
#define NCHE 18         // encoder K chunks (32 each)
#define NCHD 16         // decoder K chunks
#define NBLDS 16        // B chunks in LDS (x chunks 16/17 in regs)

typedef short bf16x8 __attribute__((ext_vector_type(8)));
typedef float f32x4 __attribute__((ext_vector_type(4)));
typedef unsigned u32x4 __attribute__((ext_vector_type(4)));
typedef unsigned u32x2 __attribute__((ext_vector_type(2)));

template<bool B> using icb = std::integral_constant<bool, B>;

__device__ __forceinline__ float sigmf(float x) { return 1.0f / (1.0f + expf(-x)); }
__device__ __forceinline__ float bf2f(unsigned short h) {
    return __uint_as_float(((unsigned)h) << 16);
}
__device__ __forceinline__ unsigned short f2bf(float x) {  // round-to-nearest-even
    unsigned u = __float_as_uint(x);
    return (unsigned short)((u + 0x7fffu + ((u >> 16) & 1u)) >> 16);
}
__device__ __forceinline__ unsigned packsplit(float v) {   // bf16 hi|lo packed
    unsigned short hi = f2bf(v);
    unsigned short lo = f2bf(v - bf2f(hi));
    return ((unsigned)hi << 16) | (unsigned)lo;
}

// Build hi/lo bf16x8 fragments from 8 packed (hi<<16|lo) words via v_perm.
__device__ __forceinline__ void mkfrag(u32x4 a, u32x4 b, bf16x8& hi, bf16x8& lo) {
    u32x4 h, l;
    h.x = __builtin_amdgcn_perm(a.y, a.x, 0x07060302u);
    h.y = __builtin_amdgcn_perm(a.w, a.z, 0x07060302u);
    h.z = __builtin_amdgcn_perm(b.y, b.x, 0x07060302u);
    h.w = __builtin_amdgcn_perm(b.w, b.z, 0x07060302u);
    l.x = __builtin_amdgcn_perm(a.y, a.x, 0x05040100u);
    l.y = __builtin_amdgcn_perm(a.w, a.z, 0x05040100u);
    l.z = __builtin_amdgcn_perm(b.y, b.x, 0x05040100u);
    l.w = __builtin_amdgcn_perm(b.w, b.z, 0x05040100u);
    hi = *(bf16x8*)&h;
    lo = *(bf16x8*)&l;
}

// ---------------------------------------------------------------------------
// Weight prep: bf16 hi/lo planes, permuted + fragment-ready, 64 jt-slabs of
// 32 gate-cols. Elem [(ch*4+ks)*32 + gc][m] holds source row gate*HD + jt*8
// + jj at k = ch*32 + ks*8 + m, with gate=gc>>3, jj=gc&7.
// ---------------------------------------------------------------------------
__global__ __launch_bounds__(128)
void prep_wfrag(const float* __restrict__ Whh, const float* __restrict__ Wih,
                unsigned short* __restrict__ Ph, unsigned short* __restrict__ Pl,
                int nch)
{
    const int jt = blockIdx.x;          // 0..63
    const int ch = blockIdx.y;
    const int ks = threadIdx.x >> 5;    // 0..3
    const int gc = threadIdx.x & 31;
    const int gate = gc >> 3;
    const int jj = gc & 7;
    const int srow = gate * HD + jt * 8 + jj;
    const int k0 = ch * 32 + ks * 8;
    const size_t o = (size_t)jt * (nch * 1024) + (size_t)((ch * 4 + ks) * 32 + gc) * 8;
    #pragma unroll
    for (int m = 0; m < 8; ++m) {
        int k = k0 + m;
        float v = (k < HD) ? Whh[(size_t)srow * HD + k] : Wih[(size_t)srow * CD + (k - HD)];
        unsigned short hi = f2bf(v);
        Ph[o + m] = hi;
        Pl[o + m] = f2bf(v - bf2f(hi));
    }
}

// ---------------------------------------------------------------------------
// x prep: (N,C,T) f32 -> packed u32, TILED: xT[t][ng][ct][64][16].
// ---------------------------------------------------------------------------
__global__ __launch_bounds__(256)
void prep_xT(const float* __restrict__ x, unsigned* __restrict__ Xt)
{
    __shared__ float tile[CD * TD];
    const int n = blockIdx.x;
    for (int e = threadIdx.x; e < CD * TD; e += 256)
        tile[e] = x[(size_t)n * CD * TD + e];
    __syncthreads();
    for (int e = threadIdx.x; e < CD * TD; e += 256) {
        int t = e >> 6, c = e & 63;
        size_t o = ((size_t)(t * 8 + (n >> 6)) * 4 + (c >> 4)) * 1024 + (n & 63) * 16 + (c & 15);
        Xt[o] = packsplit(tile[c * TD + t]);
    }
}

// ---------------------------------------------------------------------------
// Persistent encoder+decoder. 512 blocks x 256 threads (4 waves), 2 blocks/CU
// (73.7KB LDS). Block (jt = bid>>3: 8 gate-cols; ng = bid&7): tile 64n x 32gc.
// Wave w = (p2 = w>>1: n-half) x (q = w&1: chunk parity). A fragments load
// direct global->VGPR, issue pinned early via empty-asm liveness; x chunk
// computed first to cover h-load latency. B (16 chunks) LDS-resident, x-chunk
// B in regs. Partner reduction 8KB LDS; h out via LDS tile + coalesced
// sc0/sc1 dwordx2; per-ng 64-block counter barrier + agent acquire fence.
// ---------------------------------------------------------------------------
__global__ __launch_bounds__(256, 2)
void lstm_persist(const unsigned short* __restrict__ WeH, const unsigned short* __restrict__ WeL,
                  const unsigned short* __restrict__ WdH, const unsigned short* __restrict__ WdL,
                  const unsigned* __restrict__ xT,
                  const float* __restrict__ b_e, const float* __restrict__ b_d,
                  unsigned* __restrict__ hp,   // [2][NB*HD] packed, tiled
                  unsigned* __restrict__ hs,   // [DSTEPS][NB*HD] packed, tiled
                  unsigned* __restrict__ cnt)
{
    __shared__ __align__(16) unsigned short BhS[NBLDS * 1024];  // 32768 B
    __shared__ __align__(16) unsigned short BlS[NBLDS * 1024];  // 32768 B
    __shared__ __align__(16) float red[2048];                   // 8192 B (+otile overlay)

    const int tid  = threadIdx.x;
    const int lane = tid & 63;
    const int w    = tid >> 6;          // wave 0..3
    const int p2   = w >> 1;            // n-half (rows p2*32..+31)
    const int q    = w & 1;             // chunk parity
    const int jt   = blockIdx.x >> 3;   // 0..63
    const int ng   = blockIdx.x & 7;    // n-group (XCD heuristic, perf only)

    const int rs    = lane >> 4;        // frag k-slot 0..3
    const int c15   = lane & 15;
    const int pl    = (lane >> 3) & 1;
    const int jbase = jt * 8 + (lane & 7);
    // per-lane u32 offset within a 1024-u32 [64][16] tile for fragment rows:
    const int rowcol0 = (p2 * 32 + c15) * 16 + (rs & 1) * 8;        // fmL=0
    const int rowcol1 = (p2 * 32 + 16 + c15) * 16 + (rs & 1) * 8;   // fmL=1
    const int tsub    = rs >> 1;        // which of the chunk's 2 tiles

    const size_t slabE = (size_t)jt * (NCHE * 1024);
    const size_t slabD = (size_t)jt * (NCHD * 1024);
    const size_t NH    = (size_t)NB * HD;   // u32 elems per h buffer

    // Biases (4 gates at this lane's j)
    float bje[4], bjd[4];
    #pragma unroll
    for (int g = 0; g < 4; ++g) {
        bje[g] = b_e[g * HD + jbase];
        bjd[g] = b_d[g * HD + jbase];
    }

    auto stageB = [&](const unsigned short* PH, const unsigned short* PL, size_t slab) {
        for (int e = tid; e < NBLDS * 128; e += 256) {
            *(bf16x8*)&BhS[(size_t)e * 8] = *(const bf16x8*)&PH[slab + (size_t)e * 8];
            *(bf16x8*)&BlS[(size_t)e * 8] = *(const bf16x8*)&PL[slab + (size_t)e * 8];
        }
    };
    // Encoder x-chunk B (chunk 16+q) in registers (16 VGPRs/wave).
    bf16x8 xbh[2], xbl[2];
    #pragma unroll
    for (int fg = 0; fg < 2; ++fg) {
        size_t o = slabE + (size_t)(((16 + q) * 4 + rs) * 32 + fg * 16 + c15) * 8;
        xbh[fg] = *(const bf16x8*)&WeH[o];
        xbl[fg] = *(const bf16x8*)&WeL[o];
    }
    stageB(WeH, WeL, slabE);

    // x prefetch regs (chunk 16 for q=0, 17 for q=1)
    u32x4 xpend[4];
    auto loadX = [&](int t) {
        const unsigned* xb = xT + (size_t)((t * 8 + ng) * 4) * 1024;
        const unsigned* s0 = xb + (q * 2 + tsub) * 1024 + rowcol0;
        const unsigned* s1 = xb + (q * 2 + tsub) * 1024 + rowcol1;
        xpend[0] = *(const u32x4*)s0; xpend[1] = *(const u32x4*)(s0 + 4);
        xpend[2] = *(const u32x4*)s1; xpend[3] = *(const u32x4*)(s1 + 4);
    };
    loadX(0);
    __syncthreads();

    float cr[4] = {};                    // cell state [r]
    unsigned tgt = 64;
    unsigned* myc = &cnt[ng * 32];

    auto step = [&](auto HASXC,
                    const unsigned* __restrict__ hb,    // ng-offset tiled h src
                    const float (&bj)[4],
                    unsigned* __restrict__ hdst)        // full tiled base
    {
        constexpr bool HASX = decltype(HASXC)::value;
        f32x4 acc[2][2] = {};            // [fmL][fg]
        u32x4 pend[8][4];

        // Issue ALL h loads for this step; pin results live so the compiler
        // cannot sink the loads to their uses (rule #17 liveness idiom).
        #pragma unroll
        for (int i = 0; i < 8; ++i) {
            const int ch = q + 2 * i;
            const unsigned* s0 = hb + (2 * ch + tsub) * 1024 + rowcol0;
            const unsigned* s1 = hb + (2 * ch + tsub) * 1024 + rowcol1;
            pend[i][0] = *(const u32x4*)s0; pend[i][1] = *(const u32x4*)(s0 + 4);
            pend[i][2] = *(const u32x4*)s1; pend[i][3] = *(const u32x4*)(s1 + 4);
        }
        #pragma unroll
        for (int i = 0; i < 8; ++i) {
            asm volatile("" :: "v"(pend[i][0]), "v"(pend[i][1]),
                              "v"(pend[i][2]), "v"(pend[i][3]));
        }

        // x chunk FIRST (operands already in registers) — covers h latency.
        if constexpr (HASX) {
            bf16x8 ah0, al0, ah1, al1;
            mkfrag(xpend[0], xpend[1], ah0, al0);
            mkfrag(xpend[2], xpend[3], ah1, al1);
            #pragma unroll
            for (int fg = 0; fg < 2; ++fg) {
                acc[0][fg] = __builtin_amdgcn_mfma_f32_16x16x32_bf16(ah0, xbh[fg], acc[0][fg], 0, 0, 0);
                acc[0][fg] = __builtin_amdgcn_mfma_f32_16x16x32_bf16(ah0, xbl[fg], acc[0][fg], 0, 0, 0);
                acc[0][fg] = __builtin_amdgcn_mfma_f32_16x16x32_bf16(al0, xbh[fg], acc[0][fg], 0, 0, 0);
                acc[1][fg] = __builtin_amdgcn_mfma_f32_16x16x32_bf16(ah1, xbh[fg], acc[1][fg], 0, 0, 0);
                acc[1][fg] = __builtin_amdgcn_mfma_f32_16x16x32_bf16(ah1, xbl[fg], acc[1][fg], 0, 0, 0);
                acc[1][fg] = __builtin_amdgcn_mfma_f32_16x16x32_bf16(al1, xbh[fg], acc[1][fg], 0, 0, 0);
            }
        }

        // K-loop: 8 h chunks, no intra-loop barriers, counted vmcnt per use.
        #pragma unroll
        for (int i = 0; i < 8; ++i) {
            const int ch = q + 2 * i;
            bf16x8 bh[2], bl[2];
            #pragma unroll
            for (int fg = 0; fg < 2; ++fg) {
                const int bi = ((ch * 4 + rs) * 32 + fg * 16 + c15) * 8;
                bh[fg] = *(const bf16x8*)&BhS[bi];
                bl[fg] = *(const bf16x8*)&BlS[bi];
            }
            bf16x8 ah0, al0, ah1, al1;
            mkfrag(pend[i][0], pend[i][1], ah0, al0);
            mkfrag(pend[i][2], pend[i][3], ah1, al1);
            #pragma unroll
            for (int fg = 0; fg < 2; ++fg) {
                acc[0][fg] = __builtin_amdgcn_mfma_f32_16x16x32_bf16(ah0, bh[fg], acc[0][fg], 0, 0, 0);
                acc[0][fg] = __builtin_amdgcn_mfma_f32_16x16x32_bf16(ah0, bl[fg], acc[0][fg], 0, 0, 0);
                acc[0][fg] = __builtin_amdgcn_mfma_f32_16x16x32_bf16(al0, bh[fg], acc[0][fg], 0, 0, 0);
                acc[1][fg] = __builtin_amdgcn_mfma_f32_16x16x32_bf16(ah1, bh[fg], acc[1][fg], 0, 0, 0);
                acc[1][fg] = __builtin_amdgcn_mfma_f32_16x16x32_bf16(ah1, bl[fg], acc[1][fg], 0, 0, 0);
                acc[1][fg] = __builtin_amdgcn_mfma_f32_16x16x32_bf16(al1, bh[fg], acc[1][fg], 0, 0, 0);
            }
        }

        // Partner reduction: wave keeps fmL == q (static indexing only).
        f32x4 keep[2], give[2];
        if (q == 0) {
            keep[0] = acc[0][0]; keep[1] = acc[0][1];
            give[0] = acc[1][0]; give[1] = acc[1][1];
        } else {
            keep[0] = acc[1][0]; keep[1] = acc[1][1];
            give[0] = acc[0][0]; give[1] = acc[0][1];
        }
        float* myslot = &red[w * 512 + lane * 8];
        *(f32x4*)&myslot[0] = give[0];
        *(f32x4*)&myslot[4] = give[1];
        __syncthreads();
        const float* ps = &red[(w ^ 1) * 512 + lane * 8];
        keep[0] += *(const f32x4*)&ps[0];
        keep[1] += *(const f32x4*)&ps[4];
        __syncthreads();                 // red free -> otile overlay safe

        // Epilogue -> LDS out-tile [64][8] u32, then coalesced sc1 store.
        unsigned* otile = (unsigned*)red;
        #pragma unroll
        for (int r = 0; r < 4; ++r) {
            float v0 = keep[0][r], v1 = keep[1][r];
            float u0 = __shfl_xor(v0, 8, 64);
            float u1 = __shfl_xor(v1, 8, 64);
            if (pl == 0) {
                const int row = p2 * 32 + q * 16 + (lane >> 4) * 4 + r;
                float gi = v0 + bj[0], gf = u0 + bj[1];
                float gg = v1 + bj[2], go = u1 + bj[3];
                float cn = sigmf(gf) * cr[r] + sigmf(gi) * tanhf(gg);
                float hn = sigmf(go) * tanhf(cn);
                cr[r] = cn;
                otile[row * 8 + (lane & 7)] = packsplit(hn);
            }
        }
        __syncthreads();
        u32x2 hv = *(const u32x2*)&((const unsigned*)red)[tid * 2];
        unsigned* dst = hdst + (size_t)(ng * 32 + (jt >> 1)) * 1024
                        + (tid >> 2) * 16 + (jt & 1) * 8 + (tid & 3) * 2;
        asm volatile("global_store_dwordx2 %0, %1, off sc0 sc1"
                     :: "v"(dst), "v"(hv) : "memory");
    };

    auto ngbar = [&](bool xinflight) {
        // Drain only the h store (x prefetch stays in flight when present).
        if (xinflight) asm volatile("s_waitcnt vmcnt(4) lgkmcnt(0)" ::: "memory");
        else           asm volatile("s_waitcnt vmcnt(0) lgkmcnt(0)" ::: "memory");
        asm volatile("s_barrier" ::: "memory");
        if (tid == 0) {
            __hip_atomic_fetch_add(myc, 1u, __ATOMIC_RELAXED, __HIP_MEMORY_SCOPE_AGENT);
            while (__hip_atomic_load(myc, __ATOMIC_RELAXED, __HIP_MEMORY_SCOPE_AGENT) < tgt)
                __builtin_amdgcn_s_sleep(1);
        }
        asm volatile("s_barrier" ::: "memory");
        __builtin_amdgcn_fence(__ATOMIC_ACQUIRE, "agent");  // inv stale cached h
        tgt += 64;
    };

    // ---- encoder: 168 steps (even count -> h_enc lands in slot 0) ----
    for (int t = 0; t < TD; ++t) {
        step(icb<true>{},
             hp + (size_t)(t & 1) * NH + ng * 32768,
             bje,
             hp + (size_t)((t + 1) & 1) * NH);
        bool more = (t + 1 < TD);
        if (more) loadX(t + 1);          // overlaps the barrier wait
        ngbar(more);
    }

    // ---- swap in decoder weights (16 chunks) ----
    stageB(WdH, WdL, slabD);
    __syncthreads();
    #pragma unroll
    for (int r = 0; r < 4; ++r) cr[r] = 0.f;

    // ---- decoder: 24 steps, outputs land in hs slots ----
    for (int s = 0; s < DSTEPS; ++s) {
        const unsigned* hb = ((s == 0) ? hp : hs + (size_t)(s - 1) * NH) + ng * 32768;
        step(icb<false>{}, hb, bjd, hs + (size_t)s * NH);
        ngbar(false);
    }
}

// ---------------------------------------------------------------------------
// Dense head over TILED hs: out[n][o][t] = sum_k unpack(hs) * Wd + bd.
// ---------------------------------------------------------------------------
__global__ __launch_bounds__(256)
void dense_kernel(const unsigned* __restrict__ hsP,
                  const float* __restrict__ Wd,
                  const float* __restrict__ bd,
                  float* __restrict__ out)
{
    const int t  = blockIdx.y;
    const int gx = blockIdx.x;          // n-group (n0 = gx*64)
    const int tid = threadIdx.x;
    const int to  = tid & 15;
    const int tn  = tid >> 4;

    __shared__ __align__(16) float aT[32 * 68];
    __shared__ __align__(16) float wT[32 * 68];

    float acc[4][4] = {};

    for (int ch = 0; ch < HD / 32; ++ch) {
        const int k0 = ch * 32;
        __syncthreads();
        #pragma unroll
        for (int i = 0; i < 8; ++i) {
            int e  = tid + i * 256;
            int kk = e & 31;
            int nl = e >> 5;
            int k  = k0 + kk;
            unsigned v = hsP[(size_t)t * (NB * HD)
                             + (size_t)(gx * 32 + (k >> 4)) * 1024 + nl * 16 + (k & 15)];
            aT[kk * 68 + nl] = bf2f((unsigned short)(v >> 16)) + bf2f((unsigned short)(v & 0xffffu));
            wT[kk * 68 + nl] = Wd[((size_t)t * OUTC + nl) * HD + k];
        }
        __syncthreads();
        #pragma unroll
        for (int kk = 0; kk < 32; ++kk) {
            float4 a = *reinterpret_cast<const float4*>(&aT[kk * 68 + tn * 4]);
            float4 wv = *reinterpret_cast<const float4*>(&wT[kk * 68 + to * 4]);
            acc[0][0] += a.x * wv.x; acc[0][1] += a.x * wv.y; acc[0][2] += a.x * wv.z; acc[0][3] += a.x * wv.w;
            acc[1][0] += a.y * wv.x; acc[1][1] += a.y * wv.y; acc[1][2] += a.y * wv.z; acc[1][3] += a.y * wv.w;
            acc[2][0] += a.z * wv.x; acc[2][1] += a.z * wv.y; acc[2][2] += a.z * wv.z; acc[2][3] += a.z * wv.w;
            acc[3][0] += a.w * wv.x; acc[3][1] += a.w * wv.y; acc[3][2] += a.w * wv.z; acc[3][3] += a.w * wv.w;
        }
    }

    #pragma unroll
    for (int i = 0; i < 4; ++i)
        #pragma unroll
        for (int jq = 0; jq < 4; ++jq) {
            int n = gx * 64 + tn * 4 + i;
            int o = to * 4 + jq;
            out[((size_t)n * OUTC + o) * DSTEPS + t] = acc[i][jq] + bd[t * OUTC + o];
        }
}

// ---------------------------------------------------------------------------
extern "C" void kernel_launch(void* const* d_in, const int* in_sizes, int n_in,
                              void* d_out, int out_size, void* d_ws, size_t ws_size,
                              hipStream_t stream) {
    const float* x       = (const float*)d_in[0];
    const float* W_ih_e  = (const float*)d_in[1];
    const float* W_hh_e  = (const float*)d_in[2];
    const float* b_e     = (const float*)d_in[3];
    const float* W_hh_d  = (const float*)d_in[4];
    const float* b_d     = (const float*)d_in[5];
    const float* W_dense = (const float*)d_in[6];
    const float* b_dense = (const float*)d_in[7];
    float* out = (float*)d_out;

    const size_t NH = (size_t)NB * HD;   // 262144 u32 elems

    char* pws = (char*)d_ws;
    auto alloc = [&](size_t bytes) { char* q = pws; pws += (bytes + 255) & ~(size_t)255; return q; };
    unsigned short* WeH = (unsigned short*)alloc((size_t)GATES * KWE * 2);
    unsigned short* WeL = (unsigned short*)alloc((size_t)GATES * KWE * 2);
    unsigned short* WdH = (unsigned short*)alloc((size_t)GATES * HD * 2);
    unsigned short* WdL = (unsigned short*)alloc((size_t)GATES * HD * 2);
    unsigned*       xTl = (unsigned*)alloc((size_t)TD * NB * CD * 4);
    unsigned*       hp  = (unsigned*)alloc(2 * NH * 4);
    unsigned*       hs  = (unsigned*)alloc((size_t)DSTEPS * NH * 4);
    unsigned*       cnt = (unsigned*)alloc(8 * 32 * sizeof(unsigned));

    // Prep (every call; deterministic)
    prep_wfrag<<<dim3(64, NCHE), dim3(128), 0, stream>>>(W_hh_e, W_ih_e, WeH, WeL, NCHE);
    prep_wfrag<<<dim3(64, NCHD), dim3(128), 0, stream>>>(W_hh_d, W_hh_d, WdH, WdL, NCHD);
    prep_xT<<<dim3(NB), dim3(256), 0, stream>>>(x, xTl);

    (void)hipMemsetAsync(hp, 0, NH * 4, stream);                 // slot 0 = zeros
    (void)hipMemsetAsync(cnt, 0, 8 * 32 * sizeof(unsigned), stream);

    lstm_persist<<<dim3(512), dim3(256), 0, stream>>>(
        WeH, WeL, WdH, WdL, xTl, b_e, b_d, hp, hs, cnt);

    dense_kernel<<<dim3(NB / 64, DSTEPS), dim3(256), 0, stream>>>(
        hs, W_dense, b_dense, out);
}

// Round 11
// 3221.655 us; speedup vs baseline: 1.5203x; 1.5203x over previous
//
#include <hip/hip_runtime.h>
#include <math.h>
#include <type_traits>

// Problem constants
#define NB 512     // batch
#define HD 512     // hidden
#define CD 64      // in channels
#define TD 168     // encode length
#define DSTEPS 24  // decoder steps
#define OUTC 64    // out channels
#define GATES 2048 // 4*HD
#define KWE (HD + CD)   // encoder K = 576
#define NCHE 18         // encoder K chunks (32 each)
#define NCHD 16         // decoder K chunks
#define NBLDS 17        // B chunks in LDS (encoder chunk 17 in regs on q=1 waves)

typedef short bf16x8 __attribute__((ext_vector_type(8)));
typedef float f32x4 __attribute__((ext_vector_type(4)));
typedef unsigned u32x4 __attribute__((ext_vector_type(4)));   // native vec for asm "v"

template<bool B> using icb = std::integral_constant<bool, B>;

__device__ __forceinline__ float sigmf(float x) { return 1.0f / (1.0f + expf(-x)); }
__device__ __forceinline__ float bf2f(unsigned short h) {
    return __uint_as_float(((unsigned)h) << 16);
}
__device__ __forceinline__ unsigned short f2bf(float x) {  // round-to-nearest-even
    unsigned u = __float_as_uint(x);
    return (unsigned short)((u + 0x7fffu + ((u >> 16) & 1u)) >> 16);
}
__device__ __forceinline__ unsigned packsplit(float v) {   // bf16 hi|lo packed
    unsigned short hi = f2bf(v);
    unsigned short lo = f2bf(v - bf2f(hi));
    return ((unsigned)hi << 16) | (unsigned)lo;
}

// Build hi/lo bf16x8 fragments from 8 packed (hi<<16|lo) words via v_perm.
__device__ __forceinline__ void mkfrag(u32x4 a, u32x4 b, bf16x8& hi, bf16x8& lo) {
    u32x4 h, l;
    h.x = __builtin_amdgcn_perm(a.y, a.x, 0x07060302u);
    h.y = __builtin_amdgcn_perm(a.w, a.z, 0x07060302u);
    h.z = __builtin_amdgcn_perm(b.y, b.x, 0x07060302u);
    h.w = __builtin_amdgcn_perm(b.w, b.z, 0x07060302u);
    l.x = __builtin_amdgcn_perm(a.y, a.x, 0x05040100u);
    l.y = __builtin_amdgcn_perm(a.w, a.z, 0x05040100u);
    l.z = __builtin_amdgcn_perm(b.y, b.x, 0x05040100u);
    l.w = __builtin_amdgcn_perm(b.w, b.z, 0x05040100u);
    hi = *(bf16x8*)&h;
    lo = *(bf16x8*)&l;
}

// ---------------------------------------------------------------------------
// Weight prep: bf16 hi/lo planes, permuted + fragment-ready.
// Elem [(ch*4+ks)*64 + gc][m] holds source row gate*HD + jt*16 + jj at
// k = ch*32 + ks*8 + m, with gate=(gc>>3)&3, jj=(gc&7)+8*(gc>>5).
// ---------------------------------------------------------------------------
__global__ __launch_bounds__(256)
void prep_wfrag(const float* __restrict__ Whh, const float* __restrict__ Wih,
                unsigned short* __restrict__ Ph, unsigned short* __restrict__ Pl,
                int nch)
{
    const int jt = blockIdx.x, ch = blockIdx.y;
    const int ks = threadIdx.x >> 6, gc = threadIdx.x & 63;
    const int gate = (gc >> 3) & 3;
    const int jj = (gc & 7) + ((gc >> 5) << 3);
    const int srow = gate * HD + jt * 16 + jj;
    const int k0 = ch * 32 + ks * 8;
    const size_t o = (size_t)jt * (64 * nch * 32) + (size_t)((ch * 4 + ks) * 64 + gc) * 8;
    #pragma unroll
    for (int m = 0; m < 8; ++m) {
        int k = k0 + m;
        float v = (k < HD) ? Whh[(size_t)srow * HD + k] : Wih[(size_t)srow * CD + (k - HD)];
        unsigned short hi = f2bf(v);
        Ph[o + m] = hi;
        Pl[o + m] = f2bf(v - bf2f(hi));
    }
}

// ---------------------------------------------------------------------------
// x prep: (N,C,T) f32 -> packed u32, TILED: xT[t][ng][ct][64][16],
// ct = c>>4 (4 tiles of 16 channels), row = n&63, col = c&15.
// ---------------------------------------------------------------------------
__global__ __launch_bounds__(256)
void prep_xT(const float* __restrict__ x, unsigned* __restrict__ Xt)
{
    __shared__ float tile[CD * TD];
    const int n = blockIdx.x;
    for (int e = threadIdx.x; e < CD * TD; e += 256)
        tile[e] = x[(size_t)n * CD * TD + e];
    __syncthreads();
    for (int e = threadIdx.x; e < CD * TD; e += 256) {
        int t = e >> 6, c = e & 63;
        size_t o = ((size_t)(t * 8 + (n >> 6)) * 4 + (c >> 4)) * 1024 + (n & 63) * 16 + (c & 15);
        Xt[o] = packsplit(tile[c * TD + t]);
    }
}

// ---------------------------------------------------------------------------
// Persistent encoder+decoder. 256 blocks x 256 threads (4 waves), 1 block/CU.
// Identical to round 9 EXCEPT the inter-block barrier: flag-ARRAY (one store
// per block, lane-parallel coalesced poll) instead of one contended counter
// (serialized RMW chain at MALL was the suspected step-boundary cost).
// ---------------------------------------------------------------------------
__global__ __launch_bounds__(256, 1)
void lstm_persist(const unsigned short* __restrict__ WeH, const unsigned short* __restrict__ WeL,
                  const unsigned short* __restrict__ WdH, const unsigned short* __restrict__ WdL,
                  const unsigned* __restrict__ xT,
                  const float* __restrict__ b_e, const float* __restrict__ b_d,
                  unsigned* __restrict__ hp,   // [2][NB*HD] packed, tiled
                  unsigned* __restrict__ hs,   // [DSTEPS][NB*HD] packed, tiled
                  unsigned* __restrict__ flags)
{
    __shared__ __align__(16) unsigned short BhS[NBLDS * 2048];  // 69632 B
    __shared__ __align__(16) unsigned short BlS[NBLDS * 2048];  // 69632 B
    __shared__ __align__(16) float red[4 * 1280];               // 20480 B

    const int tid  = threadIdx.x;
    const int lane = tid & 63;
    const int w    = tid >> 6;          // wave 0..3
    const int p2   = w >> 1;            // fm-pair (rows p2*32..+31)
    const int q    = w & 1;             // chunk parity
    const int jt   = blockIdx.x >> 3;   // 0..31
    const int ng   = blockIdx.x & 7;    // n-group (== XCD heuristic, perf only)

    const int rs    = lane >> 4;        // frag k-slot 0..3
    const int c15   = lane & 15;
    const int pl    = (lane >> 3) & 1;
    const int jbase = jt * 16 + (lane & 7);
    // per-lane u32 offset within a 1024-u32 tile for fragment rows:
    const int rowcol0 = (p2 * 32 + c15) * 16 + (rs & 1) * 8;        // fmL=0
    const int rowcol1 = (p2 * 32 + 16 + c15) * 16 + (rs & 1) * 8;   // fmL=1
    const int tsub    = rs >> 1;        // which of the chunk's 2 tiles

    const size_t slabE = (size_t)jt * (64 * KWE);
    const size_t slabD = (size_t)jt * (64 * HD);
    const size_t NH    = (size_t)NB * HD;   // u32 elems per h buffer

    // Biases
    float bje[2][4], bjd[2][4];
    #pragma unroll
    for (int g = 0; g < 4; ++g) {
        bje[0][g] = b_e[g * HD + jbase];
        bje[1][g] = b_e[g * HD + jbase + 8];
        bjd[0][g] = b_d[g * HD + jbase];
        bjd[1][g] = b_d[g * HD + jbase + 8];
    }

    auto stageB = [&](const unsigned short* PH, const unsigned short* PL,
                      size_t slab, int nchunks) {
        for (int e = tid; e < nchunks * 256; e += 256) {
            *(bf16x8*)&BhS[(size_t)e * 8] = *(const bf16x8*)&PH[slab + (size_t)e * 8];
            *(bf16x8*)&BlS[(size_t)e * 8] = *(const bf16x8*)&PL[slab + (size_t)e * 8];
        }
    };
    // Encoder tail B chunk (17) in regs on q==1 waves.
    bf16x8 tbh[4], tbl[4];
    if (q == 1) {
        #pragma unroll
        for (int fg = 0; fg < 4; ++fg) {
            size_t o = slabE + (size_t)((17 * 4 + rs) * 64 + fg * 16 + c15) * 8;
            tbh[fg] = *(const bf16x8*)&WeH[o];
            tbl[fg] = *(const bf16x8*)&WeL[o];
        }
    }
    stageB(WeH, WeL, slabE, NBLDS);

    // x prefetch regs (chunk 16 for q=0, 17 for q=1)
    u32x4 xpend[4];
    auto loadX = [&](int t) {
        const unsigned* xb = xT + (size_t)((t * 8 + ng) * 4) * 1024;
        const unsigned* s0 = xb + (q * 2 + tsub) * 1024 + rowcol0;
        const unsigned* s1 = xb + (q * 2 + tsub) * 1024 + rowcol1;
        xpend[0] = *(const u32x4*)s0; xpend[1] = *(const u32x4*)(s0 + 4);
        xpend[2] = *(const u32x4*)s1; xpend[3] = *(const u32x4*)(s1 + 4);
    };
    loadX(0);
    __syncthreads();

    float cr[2][4] = {};                 // cell state [jjhi][r]
    unsigned tgt = 1;                    // monotonic step id (flag value)
    unsigned* myflags = &flags[ng * 32]; // this n-group's 32 arrival slots

    auto step = [&](auto HASXC,
                    const unsigned* __restrict__ hb,    // ng-offset tiled h src
                    const float (&bj)[2][4],
                    unsigned* __restrict__ hdst)        // full tiled base
    {
        constexpr bool HASX = decltype(HASXC)::value;
        f32x4 acc[2][4] = {};            // [fmL][fg]
        u32x4 pend[8][4];

        // Issue ALL h loads for this step (coalesced 1KB windows per instr).
        #pragma unroll
        for (int i = 0; i < 8; ++i) {
            const int ch = q + 2 * i;
            const unsigned* s0 = hb + (2 * ch + tsub) * 1024 + rowcol0;
            const unsigned* s1 = hb + (2 * ch + tsub) * 1024 + rowcol1;
            pend[i][0] = *(const u32x4*)s0; pend[i][1] = *(const u32x4*)(s0 + 4);
            pend[i][2] = *(const u32x4*)s1; pend[i][3] = *(const u32x4*)(s1 + 4);
        }

        // K-loop: 8 h chunks (+1 x chunk), no intra-loop barriers.
        #pragma unroll
        for (int i = 0; i < 8; ++i) {
            const int ch = q + 2 * i;
            bf16x8 bh[4], bl[4];
            #pragma unroll
            for (int fg = 0; fg < 4; ++fg) {
                const int bi = ((ch * 4 + rs) * 64 + fg * 16 + c15) * 8;
                bh[fg] = *(const bf16x8*)&BhS[bi];
                bl[fg] = *(const bf16x8*)&BlS[bi];
            }
            bf16x8 ah0, al0, ah1, al1;
            mkfrag(pend[i][0], pend[i][1], ah0, al0);
            mkfrag(pend[i][2], pend[i][3], ah1, al1);
            #pragma unroll
            for (int fg = 0; fg < 4; ++fg) {
                acc[0][fg] = __builtin_amdgcn_mfma_f32_16x16x32_bf16(ah0, bh[fg], acc[0][fg], 0, 0, 0);
                acc[0][fg] = __builtin_amdgcn_mfma_f32_16x16x32_bf16(ah0, bl[fg], acc[0][fg], 0, 0, 0);
                acc[0][fg] = __builtin_amdgcn_mfma_f32_16x16x32_bf16(al0, bh[fg], acc[0][fg], 0, 0, 0);
                acc[1][fg] = __builtin_amdgcn_mfma_f32_16x16x32_bf16(ah1, bh[fg], acc[1][fg], 0, 0, 0);
                acc[1][fg] = __builtin_amdgcn_mfma_f32_16x16x32_bf16(ah1, bl[fg], acc[1][fg], 0, 0, 0);
                acc[1][fg] = __builtin_amdgcn_mfma_f32_16x16x32_bf16(al1, bh[fg], acc[1][fg], 0, 0, 0);
            }
        }
        if constexpr (HASX) {            // x chunk (16 on q=0, 17 on q=1)
            bf16x8 bh[4], bl[4];
            if (q == 0) {
                #pragma unroll
                for (int fg = 0; fg < 4; ++fg) {
                    const int bi = ((16 * 4 + rs) * 64 + fg * 16 + c15) * 8;
                    bh[fg] = *(const bf16x8*)&BhS[bi];
                    bl[fg] = *(const bf16x8*)&BlS[bi];
                }
            } else {
                #pragma unroll
                for (int fg = 0; fg < 4; ++fg) { bh[fg] = tbh[fg]; bl[fg] = tbl[fg]; }
            }
            bf16x8 ah0, al0, ah1, al1;
            mkfrag(xpend[0], xpend[1], ah0, al0);
            mkfrag(xpend[2], xpend[3], ah1, al1);
            #pragma unroll
            for (int fg = 0; fg < 4; ++fg) {
                acc[0][fg] = __builtin_amdgcn_mfma_f32_16x16x32_bf16(ah0, bh[fg], acc[0][fg], 0, 0, 0);
                acc[0][fg] = __builtin_amdgcn_mfma_f32_16x16x32_bf16(ah0, bl[fg], acc[0][fg], 0, 0, 0);
                acc[0][fg] = __builtin_amdgcn_mfma_f32_16x16x32_bf16(al0, bh[fg], acc[0][fg], 0, 0, 0);
                acc[1][fg] = __builtin_amdgcn_mfma_f32_16x16x32_bf16(ah1, bh[fg], acc[1][fg], 0, 0, 0);
                acc[1][fg] = __builtin_amdgcn_mfma_f32_16x16x32_bf16(ah1, bl[fg], acc[1][fg], 0, 0, 0);
                acc[1][fg] = __builtin_amdgcn_mfma_f32_16x16x32_bf16(al1, bh[fg], acc[1][fg], 0, 0, 0);
            }
        }

        // Partner reduction: wave w keeps fm = w (static acc indexing only).
        f32x4 keep[4], give[4];
        if (q == 0) {
            #pragma unroll
            for (int fg = 0; fg < 4; ++fg) { keep[fg] = acc[0][fg]; give[fg] = acc[1][fg]; }
        } else {
            #pragma unroll
            for (int fg = 0; fg < 4; ++fg) { keep[fg] = acc[1][fg]; give[fg] = acc[0][fg]; }
        }
        float* myslot = &red[w * 1280 + lane * 20];
        #pragma unroll
        for (int fg = 0; fg < 4; ++fg) *(f32x4*)&myslot[fg * 4] = give[fg];
        __syncthreads();
        const float* ps = &red[(w ^ 1) * 1280 + lane * 20];
        #pragma unroll
        for (int fg = 0; fg < 4; ++fg) keep[fg] += *(const f32x4*)&ps[fg * 4];
        __syncthreads();                 // red free -> otile overlay safe

        // Epilogue -> LDS out-tile (4KB), then coalesced sc1 store.
        unsigned* otile = (unsigned*)red;
        #pragma unroll
        for (int r = 0; r < 4; ++r) {
            float v0 = keep[0][r], v1 = keep[1][r];
            float v2 = keep[2][r], v3 = keep[3][r];
            float u0 = __shfl_xor(v0, 8, 64);
            float u1 = __shfl_xor(v1, 8, 64);
            float u2 = __shfl_xor(v2, 8, 64);
            float u3 = __shfl_xor(v3, 8, 64);
            if (pl == 0) {
                const int row = w * 16 + (lane >> 4) * 4 + r;
                {
                    float gi = v0 + bj[0][0], gf = u0 + bj[0][1];
                    float gg = v1 + bj[0][2], go = u1 + bj[0][3];
                    float cn = sigmf(gf) * cr[0][r] + sigmf(gi) * tanhf(gg);
                    float hn = sigmf(go) * tanhf(cn);
                    cr[0][r] = cn;
                    otile[row * 16 + (lane & 7)] = packsplit(hn);
                }
                {
                    float gi = v2 + bj[1][0], gf = u2 + bj[1][1];
                    float gg = v3 + bj[1][2], go = u3 + bj[1][3];
                    float cn = sigmf(gf) * cr[1][r] + sigmf(gi) * tanhf(gg);
                    float hn = sigmf(go) * tanhf(cn);
                    cr[1][r] = cn;
                    otile[row * 16 + (lane & 7) + 8] = packsplit(hn);
                }
            }
        }
        __syncthreads();
        u32x4 hv = *(const u32x4*)&otile[tid * 4];
        unsigned* dst = hdst + (size_t)(ng * 32 + jt) * 1024 + tid * 4;
        asm volatile("global_store_dwordx4 %0, %1, off sc0 sc1"
                     :: "v"(dst), "v"(hv) : "memory");
    };

    auto ngbar = [&](bool xinflight) {
        // Drain only the h store (x prefetch stays in flight when present).
        if (xinflight) asm volatile("s_waitcnt vmcnt(4) lgkmcnt(0)" ::: "memory");
        else           asm volatile("s_waitcnt vmcnt(0) lgkmcnt(0)" ::: "memory");
        asm volatile("s_barrier" ::: "memory");
        // Flag-array barrier: one store per block (no RMW), lane-parallel
        // coalesced poll of all 32 arrival flags by wave 0.
        if (w == 0) {
            if (lane == 0)
                __hip_atomic_store(&myflags[jt], tgt,
                                   __ATOMIC_RELAXED, __HIP_MEMORY_SCOPE_AGENT);
            for (;;) {
                unsigned v = __hip_atomic_load(&myflags[lane & 31],
                                               __ATOMIC_RELAXED, __HIP_MEMORY_SCOPE_AGENT);
                if (__all(v >= tgt)) break;
                __builtin_amdgcn_s_sleep(2);
            }
        }
        asm volatile("s_barrier" ::: "memory");
        __builtin_amdgcn_fence(__ATOMIC_ACQUIRE, "agent");  // inv stale cached h
        tgt += 1;
    };

    // ---- encoder: 168 steps (even count -> h_enc lands in slot 0) ----
    for (int t = 0; t < TD; ++t) {
        step(icb<true>{},
             hp + (size_t)(t & 1) * NH + ng * 32768,
             bje,
             hp + (size_t)((t + 1) & 1) * NH);
        bool more = (t + 1 < TD);
        if (more) loadX(t + 1);          // overlaps the barrier wait
        ngbar(more);
    }

    // ---- swap in decoder weights ----
    stageB(WdH, WdL, slabD, NCHD);
    __syncthreads();
    #pragma unroll
    for (int jj = 0; jj < 2; ++jj)
        #pragma unroll
        for (int r = 0; r < 4; ++r) cr[jj][r] = 0.f;

    // ---- decoder: 24 steps, outputs land in hs slots ----
    for (int s = 0; s < DSTEPS; ++s) {
        const unsigned* hb = ((s == 0) ? hp : hs + (size_t)(s - 1) * NH) + ng * 32768;
        step(icb<false>{}, hb, bjd, hs + (size_t)s * NH);
        ngbar(false);
    }
}

// ---------------------------------------------------------------------------
// Dense head over TILED hs: out[n][o][t] = sum_k unpack(hs) * Wd + bd.
// ---------------------------------------------------------------------------
__global__ __launch_bounds__(256)
void dense_kernel(const unsigned* __restrict__ hsP,
                  const float* __restrict__ Wd,
                  const float* __restrict__ bd,
                  float* __restrict__ out)
{
    const int t  = blockIdx.y;
    const int gx = blockIdx.x;          // n-group (n0 = gx*64)
    const int tid = threadIdx.x;
    const int to  = tid & 15;
    const int tn  = tid >> 4;

    __shared__ __align__(16) float aT[32 * 68];
    __shared__ __align__(16) float wT[32 * 68];

    float acc[4][4] = {};

    for (int ch = 0; ch < HD / 32; ++ch) {
        const int k0 = ch * 32;
        __syncthreads();
        #pragma unroll
        for (int i = 0; i < 8; ++i) {
            int e  = tid + i * 256;
            int kk = e & 31;
            int nl = e >> 5;
            int k  = k0 + kk;
            unsigned v = hsP[(size_t)t * (NB * HD)
                             + (size_t)(gx * 32 + (k >> 4)) * 1024 + nl * 16 + (k & 15)];
            aT[kk * 68 + nl] = bf2f((unsigned short)(v >> 16)) + bf2f((unsigned short)(v & 0xffffu));
            wT[kk * 68 + nl] = Wd[((size_t)t * OUTC + nl) * HD + k];
        }
        __syncthreads();
        #pragma unroll
        for (int kk = 0; kk < 32; ++kk) {
            float4 a = *reinterpret_cast<const float4*>(&aT[kk * 68 + tn * 4]);
            float4 wv = *reinterpret_cast<const float4*>(&wT[kk * 68 + to * 4]);
            acc[0][0] += a.x * wv.x; acc[0][1] += a.x * wv.y; acc[0][2] += a.x * wv.z; acc[0][3] += a.x * wv.w;
            acc[1][0] += a.y * wv.x; acc[1][1] += a.y * wv.y; acc[1][2] += a.y * wv.z; acc[1][3] += a.y * wv.w;
            acc[2][0] += a.z * wv.x; acc[2][1] += a.z * wv.y; acc[2][2] += a.z * wv.z; acc[2][3] += a.z * wv.w;
            acc[3][0] += a.w * wv.x; acc[3][1] += a.w * wv.y; acc[3][2] += a.w * wv.z; acc[3][3] += a.w * wv.w;
        }
    }

    #pragma unroll
    for (int i = 0; i < 4; ++i)
        #pragma unroll
        for (int jq = 0; jq < 4; ++jq) {
            int n = gx * 64 + tn * 4 + i;
            int o = to * 4 + jq;
            out[((size_t)n * OUTC + o) * DSTEPS + t] = acc[i][jq] + bd[t * OUTC + o];
        }
}

// ---------------------------------------------------------------------------
extern "C" void kernel_launch(void* const* d_in, const int* in_sizes, int n_in,
                              void* d_out, int out_size, void* d_ws, size_t ws_size,
                              hipStream_t stream) {
    const float* x       = (const float*)d_in[0];
    const float* W_ih_e  = (const float*)d_in[1];
    const float* W_hh_e  = (const float*)d_in[2];
    const float* b_e     = (const float*)d_in[3];
    const float* W_hh_d  = (const float*)d_in[4];
    const float* b_d     = (const float*)d_in[5];
    const float* W_dense = (const float*)d_in[6];
    const float* b_dense = (const float*)d_in[7];
    float* out = (float*)d_out;

    const size_t NH = (size_t)NB * HD;   // 262144 u32 elems

    char* pws = (char*)d_ws;
    auto alloc = [&](size_t bytes) { char* q = pws; pws += (bytes + 255) & ~(size_t)255; return q; };
    unsigned short* WeH = (unsigned short*)alloc((size_t)GATES * KWE * 2);
    unsigned short* WeL = (unsigned short*)alloc((size_t)GATES * KWE * 2);
    unsigned short* WdH = (unsigned short*)alloc((size_t)GATES * HD * 2);
    unsigned short* WdL = (unsigned short*)alloc((size_t)GATES * HD * 2);
    unsigned*       xTl = (unsigned*)alloc((size_t)TD * NB * CD * 4);
    unsigned*       hp  = (unsigned*)alloc(2 * NH * 4);
    unsigned*       hs  = (unsigned*)alloc((size_t)DSTEPS * NH * 4);
    unsigned*       flg = (unsigned*)alloc(8 * 32 * sizeof(unsigned));

    // Prep (every call; deterministic)
    prep_wfrag<<<dim3(32, NCHE), dim3(256), 0, stream>>>(W_hh_e, W_ih_e, WeH, WeL, NCHE);
    prep_wfrag<<<dim3(32, NCHD), dim3(256), 0, stream>>>(W_hh_d, W_hh_d, WdH, WdL, NCHD);
    prep_xT<<<dim3(NB), dim3(256), 0, stream>>>(x, xTl);

    (void)hipMemsetAsync(hp, 0, NH * 4, stream);                 // slot 0 = zeros
    (void)hipMemsetAsync(flg, 0, 8 * 32 * sizeof(unsigned), stream);

    lstm_persist<<<dim3(256), dim3(256), 0, stream>>>(
        WeH, WeL, WdH, WdL, xTl, b_e, b_d, hp, hs, flg);

    dense_kernel<<<dim3(NB / 64, DSTEPS), dim3(256), 0, stream>>>(
        hs, W_dense, b_dense, out);
}

// Round 13
// 3040.786 us; speedup vs baseline: 1.6107x; 1.0595x over previous
//
#include <hip/hip_runtime.h>
#include <math.h>
#include <type_traits>

// Problem constants
#define NB 512     // batch
#define HD 512     // hidden
#define CD 64      // in channels
#define TD 168     // encode length
#define DSTEPS 24  // decoder steps
#define OUTC 64    // out channels
#define GATES 2048 // 4*HD
#define KWE (HD + CD)   // encoder K = 576
#define NCHE 18         // encoder K chunks (32 each)
#define NCHD 16         // decoder K chunks
#define NBLDS 17        // B chunks in LDS (encoder chunk 17 in regs on q=1 waves)

typedef short bf16x8 __attribute__((ext_vector_type(8)));
typedef float f32x4 __attribute__((ext_vector_type(4)));
typedef unsigned u32x4 __attribute__((ext_vector_type(4)));

template<bool B> using icb = std::integral_constant<bool, B>;

// Counted wait + scheduler fence (rule #18: hipcc hoists reg-only MFMA past
// inline-asm waitcnt; sched_barrier(0) right after is the required fence).
#define WAITV(N) do { asm volatile("s_waitcnt vmcnt(" #N ")" ::: "memory"); \
                      __builtin_amdgcn_sched_barrier(0); } while (0)

__device__ __forceinline__ float sigmf(float x) { return 1.0f / (1.0f + expf(-x)); }
__device__ __forceinline__ float bf2f(unsigned short h) {
    return __uint_as_float(((unsigned)h) << 16);
}
__device__ __forceinline__ unsigned short f2bf(float x) {  // round-to-nearest-even
    unsigned u = __float_as_uint(x);
    return (unsigned short)((u + 0x7fffu + ((u >> 16) & 1u)) >> 16);
}
__device__ __forceinline__ unsigned packsplit(float v) {   // bf16 hi|lo packed
    unsigned short hi = f2bf(v);
    unsigned short lo = f2bf(v - bf2f(hi));
    return ((unsigned)hi << 16) | (unsigned)lo;
}

// Build hi/lo bf16x8 fragments from 8 packed (hi<<16|lo) words via v_perm.
__device__ __forceinline__ void mkfrag(u32x4 a, u32x4 b, bf16x8& hi, bf16x8& lo) {
    u32x4 h, l;
    h.x = __builtin_amdgcn_perm(a.y, a.x, 0x07060302u);
    h.y = __builtin_amdgcn_perm(a.w, a.z, 0x07060302u);
    h.z = __builtin_amdgcn_perm(b.y, b.x, 0x07060302u);
    h.w = __builtin_amdgcn_perm(b.w, b.z, 0x07060302u);
    l.x = __builtin_amdgcn_perm(a.y, a.x, 0x05040100u);
    l.y = __builtin_amdgcn_perm(a.w, a.z, 0x05040100u);
    l.z = __builtin_amdgcn_perm(b.y, b.x, 0x05040100u);
    l.w = __builtin_amdgcn_perm(b.w, b.z, 0x05040100u);
    hi = *(bf16x8*)&h;
    lo = *(bf16x8*)&l;
}

// Two 16B loads with pinned issue position (asm volatile order is preserved;
// the compiler cannot sink these to their uses). Plain loads: r11's proven
// fence/invalidate protocol makes them correct.
__device__ __forceinline__ void ld2g(const unsigned* p, u32x4& a, u32x4& b) {
    asm volatile("global_load_dwordx4 %0, %2, off\n\t"
                 "global_load_dwordx4 %1, %2, off offset:16"
                 : "=&v"(a), "=&v"(b) : "v"(p));
}

// ---------------------------------------------------------------------------
// Weight prep: bf16 hi/lo planes, permuted + fragment-ready.
// Elem [(ch*4+ks)*64 + gc][m] holds source row gate*HD + jt*16 + jj at
// k = ch*32 + ks*8 + m, with gate=(gc>>3)&3, jj=(gc&7)+8*(gc>>5).
// ---------------------------------------------------------------------------
__global__ __launch_bounds__(256)
void prep_wfrag(const float* __restrict__ Whh, const float* __restrict__ Wih,
                unsigned short* __restrict__ Ph, unsigned short* __restrict__ Pl,
                int nch)
{
    const int jt = blockIdx.x, ch = blockIdx.y;
    const int ks = threadIdx.x >> 6, gc = threadIdx.x & 63;
    const int gate = (gc >> 3) & 3;
    const int jj = (gc & 7) + ((gc >> 5) << 3);
    const int srow = gate * HD + jt * 16 + jj;
    const int k0 = ch * 32 + ks * 8;
    const size_t o = (size_t)jt * (64 * nch * 32) + (size_t)((ch * 4 + ks) * 64 + gc) * 8;
    #pragma unroll
    for (int m = 0; m < 8; ++m) {
        int k = k0 + m;
        float v = (k < HD) ? Whh[(size_t)srow * HD + k] : Wih[(size_t)srow * CD + (k - HD)];
        unsigned short hi = f2bf(v);
        Ph[o + m] = hi;
        Pl[o + m] = f2bf(v - bf2f(hi));
    }
}

// ---------------------------------------------------------------------------
// x prep: (N,C,T) f32 -> packed u32, TILED: xT[t][ng][ct][64][16].
// ---------------------------------------------------------------------------
__global__ __launch_bounds__(256)
void prep_xT(const float* __restrict__ x, unsigned* __restrict__ Xt)
{
    __shared__ float tile[CD * TD];
    const int n = blockIdx.x;
    for (int e = threadIdx.x; e < CD * TD; e += 256)
        tile[e] = x[(size_t)n * CD * TD + e];
    __syncthreads();
    for (int e = threadIdx.x; e < CD * TD; e += 256) {
        int t = e >> 6, c = e & 63;
        size_t o = ((size_t)(t * 8 + (n >> 6)) * 4 + (c >> 4)) * 1024 + (n & 63) * 16 + (c & 15);
        Xt[o] = packsplit(tile[c * TD + t]);
    }
}

// ---------------------------------------------------------------------------
// Persistent encoder+decoder. 256 blocks x 256 threads (4 waves), 1 block/CU.
// Identical to round 11 (proven) EXCEPT: all 32 h loads per step are issued
// up front via inline-asm (pinned issue position) and consumed through a
// counted vmcnt ladder (one MALL latency per step, not eight); x chunk
// computes first to cover chunk-0 latency.
// ---------------------------------------------------------------------------
__global__ __launch_bounds__(256, 1)
void lstm_persist(const unsigned short* __restrict__ WeH, const unsigned short* __restrict__ WeL,
                  const unsigned short* __restrict__ WdH, const unsigned short* __restrict__ WdL,
                  const unsigned* __restrict__ xT,
                  const float* __restrict__ b_e, const float* __restrict__ b_d,
                  unsigned* __restrict__ hp,   // [2][NB*HD] packed, tiled
                  unsigned* __restrict__ hs,   // [DSTEPS][NB*HD] packed, tiled
                  unsigned* __restrict__ flags)
{
    __shared__ __align__(16) unsigned short BhS[NBLDS * 2048];  // 69632 B
    __shared__ __align__(16) unsigned short BlS[NBLDS * 2048];  // 69632 B
    __shared__ __align__(16) float red[4 * 1280];               // 20480 B

    const int tid  = threadIdx.x;
    const int lane = tid & 63;
    const int w    = tid >> 6;          // wave 0..3
    const int p2   = w >> 1;            // fm-pair (rows p2*32..+31)
    const int q    = w & 1;             // chunk parity
    const int jt   = blockIdx.x >> 3;   // 0..31
    const int ng   = blockIdx.x & 7;    // n-group (== XCD heuristic, perf only)

    const int rs    = lane >> 4;        // frag k-slot 0..3
    const int c15   = lane & 15;
    const int pl    = (lane >> 3) & 1;
    const int jbase = jt * 16 + (lane & 7);
    const int rowcol0 = (p2 * 32 + c15) * 16 + (rs & 1) * 8;        // fmL=0
    const int rowcol1 = (p2 * 32 + 16 + c15) * 16 + (rs & 1) * 8;   // fmL=1
    const int tsub    = rs >> 1;        // which of the chunk's 2 tiles

    const size_t slabE = (size_t)jt * (64 * KWE);
    const size_t slabD = (size_t)jt * (64 * HD);
    const size_t NH    = (size_t)NB * HD;   // u32 elems per h buffer

    // Biases
    float bje[2][4], bjd[2][4];
    #pragma unroll
    for (int g = 0; g < 4; ++g) {
        bje[0][g] = b_e[g * HD + jbase];
        bje[1][g] = b_e[g * HD + jbase + 8];
        bjd[0][g] = b_d[g * HD + jbase];
        bjd[1][g] = b_d[g * HD + jbase + 8];
    }

    auto stageB = [&](const unsigned short* PH, const unsigned short* PL,
                      size_t slab, int nchunks) {
        for (int e = tid; e < nchunks * 256; e += 256) {
            *(bf16x8*)&BhS[(size_t)e * 8] = *(const bf16x8*)&PH[slab + (size_t)e * 8];
            *(bf16x8*)&BlS[(size_t)e * 8] = *(const bf16x8*)&PL[slab + (size_t)e * 8];
        }
    };
    // Encoder tail B chunk (17) in regs on q==1 waves.
    bf16x8 tbh[4], tbl[4];
    if (q == 1) {
        #pragma unroll
        for (int fg = 0; fg < 4; ++fg) {
            size_t o = slabE + (size_t)((17 * 4 + rs) * 64 + fg * 16 + c15) * 8;
            tbh[fg] = *(const bf16x8*)&WeH[o];
            tbl[fg] = *(const bf16x8*)&WeL[o];
        }
    }
    stageB(WeH, WeL, slabE, NBLDS);

    // x prefetch regs (chunk 16 for q=0, 17 for q=1) — asm loads so the
    // step's vmcnt ladder counts are exact (x = 4 oldest outstanding).
    u32x4 xpend[4];
    auto loadX = [&](int t) {
        const unsigned* xb = xT + (size_t)((t * 8 + ng) * 4) * 1024;
        ld2g(xb + (q * 2 + tsub) * 1024 + rowcol0, xpend[0], xpend[1]);
        ld2g(xb + (q * 2 + tsub) * 1024 + rowcol1, xpend[2], xpend[3]);
    };
    loadX(0);
    asm volatile("s_waitcnt vmcnt(0)" ::: "memory");
    __syncthreads();

    float cr[2][4] = {};                 // cell state [jjhi][r]
    unsigned tgt = 1;                    // monotonic step id (flag value)
    unsigned* myflags = &flags[ng * 32];

    auto step = [&](auto HASXC,
                    const unsigned* __restrict__ hb,    // ng-offset tiled h src
                    const float (&bj)[2][4],
                    unsigned* __restrict__ hdst)        // full tiled base
    {
        constexpr bool HASX = decltype(HASXC)::value;
        f32x4 acc[2][4] = {};            // [fmL][fg]
        u32x4 pd[8][4];

        // Issue ALL 32 h loads now (asm: cannot be sunk). Outstanding after
        // this: [4 x-loads (encoder, oldest)] + 32 h loads.
        #pragma unroll
        for (int i = 0; i < 8; ++i) {
            const int ch = q + 2 * i;
            ld2g(hb + (2 * ch + tsub) * 1024 + rowcol0, pd[i][0], pd[i][1]);
            ld2g(hb + (2 * ch + tsub) * 1024 + rowcol1, pd[i][2], pd[i][3]);
        }

        // x chunk FIRST: wait only the 4 oldest (x), compute while h flies.
        if constexpr (HASX) {
            WAITV(32);
            bf16x8 bh[4], bl[4];
            if (q == 0) {
                #pragma unroll
                for (int fg = 0; fg < 4; ++fg) {
                    const int bi = ((16 * 4 + rs) * 64 + fg * 16 + c15) * 8;
                    bh[fg] = *(const bf16x8*)&BhS[bi];
                    bl[fg] = *(const bf16x8*)&BlS[bi];
                }
            } else {
                #pragma unroll
                for (int fg = 0; fg < 4; ++fg) { bh[fg] = tbh[fg]; bl[fg] = tbl[fg]; }
            }
            bf16x8 ah0, al0, ah1, al1;
            mkfrag(xpend[0], xpend[1], ah0, al0);
            mkfrag(xpend[2], xpend[3], ah1, al1);
            #pragma unroll
            for (int fg = 0; fg < 4; ++fg) {
                acc[0][fg] = __builtin_amdgcn_mfma_f32_16x16x32_bf16(ah0, bh[fg], acc[0][fg], 0, 0, 0);
                acc[0][fg] = __builtin_amdgcn_mfma_f32_16x16x32_bf16(ah0, bl[fg], acc[0][fg], 0, 0, 0);
                acc[0][fg] = __builtin_amdgcn_mfma_f32_16x16x32_bf16(al0, bh[fg], acc[0][fg], 0, 0, 0);
                acc[1][fg] = __builtin_amdgcn_mfma_f32_16x16x32_bf16(ah1, bh[fg], acc[1][fg], 0, 0, 0);
                acc[1][fg] = __builtin_amdgcn_mfma_f32_16x16x32_bf16(ah1, bl[fg], acc[1][fg], 0, 0, 0);
                acc[1][fg] = __builtin_amdgcn_mfma_f32_16x16x32_bf16(al1, bh[fg], acc[1][fg], 0, 0, 0);
            }
        }

        // K-loop: counted vmcnt ladder releases one chunk at a time.
        // Chunk i needs its 4 loads done -> allowed outstanding = 28 - 4i
        // (identical for encoder/decoder: the 4 x-loads add to both sides).
        #pragma unroll
        for (int i = 0; i < 8; ++i) {
            if      (i == 0) WAITV(28);
            else if (i == 1) WAITV(24);
            else if (i == 2) WAITV(20);
            else if (i == 3) WAITV(16);
            else if (i == 4) WAITV(12);
            else if (i == 5) WAITV(8);
            else if (i == 6) WAITV(4);
            else             WAITV(0);

            const int ch = q + 2 * i;
            bf16x8 bh[4], bl[4];
            #pragma unroll
            for (int fg = 0; fg < 4; ++fg) {
                const int bi = ((ch * 4 + rs) * 64 + fg * 16 + c15) * 8;
                bh[fg] = *(const bf16x8*)&BhS[bi];
                bl[fg] = *(const bf16x8*)&BlS[bi];
            }
            bf16x8 ah0, al0, ah1, al1;
            mkfrag(pd[i][0], pd[i][1], ah0, al0);
            mkfrag(pd[i][2], pd[i][3], ah1, al1);
            #pragma unroll
            for (int fg = 0; fg < 4; ++fg) {
                acc[0][fg] = __builtin_amdgcn_mfma_f32_16x16x32_bf16(ah0, bh[fg], acc[0][fg], 0, 0, 0);
                acc[0][fg] = __builtin_amdgcn_mfma_f32_16x16x32_bf16(ah0, bl[fg], acc[0][fg], 0, 0, 0);
                acc[0][fg] = __builtin_amdgcn_mfma_f32_16x16x32_bf16(al0, bh[fg], acc[0][fg], 0, 0, 0);
                acc[1][fg] = __builtin_amdgcn_mfma_f32_16x16x32_bf16(ah1, bh[fg], acc[1][fg], 0, 0, 0);
                acc[1][fg] = __builtin_amdgcn_mfma_f32_16x16x32_bf16(ah1, bl[fg], acc[1][fg], 0, 0, 0);
                acc[1][fg] = __builtin_amdgcn_mfma_f32_16x16x32_bf16(al1, bh[fg], acc[1][fg], 0, 0, 0);
            }
        }

        // Partner reduction: wave w keeps fm = w (static acc indexing only).
        f32x4 keep[4], give[4];
        if (q == 0) {
            #pragma unroll
            for (int fg = 0; fg < 4; ++fg) { keep[fg] = acc[0][fg]; give[fg] = acc[1][fg]; }
        } else {
            #pragma unroll
            for (int fg = 0; fg < 4; ++fg) { keep[fg] = acc[1][fg]; give[fg] = acc[0][fg]; }
        }
        float* myslot = &red[w * 1280 + lane * 20];
        #pragma unroll
        for (int fg = 0; fg < 4; ++fg) *(f32x4*)&myslot[fg * 4] = give[fg];
        __syncthreads();
        const float* ps = &red[(w ^ 1) * 1280 + lane * 20];
        #pragma unroll
        for (int fg = 0; fg < 4; ++fg) keep[fg] += *(const f32x4*)&ps[fg * 4];
        __syncthreads();                 // red free -> otile overlay safe

        // Epilogue -> LDS out-tile (4KB), then coalesced sc1 store.
        unsigned* otile = (unsigned*)red;
        #pragma unroll
        for (int r = 0; r < 4; ++r) {
            float v0 = keep[0][r], v1 = keep[1][r];
            float v2 = keep[2][r], v3 = keep[3][r];
            float u0 = __shfl_xor(v0, 8, 64);
            float u1 = __shfl_xor(v1, 8, 64);
            float u2 = __shfl_xor(v2, 8, 64);
            float u3 = __shfl_xor(v3, 8, 64);
            if (pl == 0) {
                const int row = w * 16 + (lane >> 4) * 4 + r;
                {
                    float gi = v0 + bj[0][0], gf = u0 + bj[0][1];
                    float gg = v1 + bj[0][2], go = u1 + bj[0][3];
                    float cn = sigmf(gf) * cr[0][r] + sigmf(gi) * tanhf(gg);
                    float hn = sigmf(go) * tanhf(cn);
                    cr[0][r] = cn;
                    otile[row * 16 + (lane & 7)] = packsplit(hn);
                }
                {
                    float gi = v2 + bj[1][0], gf = u2 + bj[1][1];
                    float gg = v3 + bj[1][2], go = u3 + bj[1][3];
                    float cn = sigmf(gf) * cr[1][r] + sigmf(gi) * tanhf(gg);
                    float hn = sigmf(go) * tanhf(cn);
                    cr[1][r] = cn;
                    otile[row * 16 + (lane & 7) + 8] = packsplit(hn);
                }
            }
        }
        __syncthreads();
        u32x4 hv = *(const u32x4*)&otile[tid * 4];
        unsigned* dst = hdst + (size_t)(ng * 32 + jt) * 1024 + tid * 4;
        asm volatile("global_store_dwordx4 %0, %1, off sc0 sc1"
                     :: "v"(dst), "v"(hv) : "memory");
    };

    auto ngbar = [&](bool xinflight) {
        // Drain only the h store (x prefetch stays in flight when present;
        // store is oldest of [store, x0..x3] -> vmcnt(4) drains exactly it).
        if (xinflight) asm volatile("s_waitcnt vmcnt(4) lgkmcnt(0)" ::: "memory");
        else           asm volatile("s_waitcnt vmcnt(0) lgkmcnt(0)" ::: "memory");
        asm volatile("s_barrier" ::: "memory");
        // Flag-array barrier: one store per block (no RMW), lane-parallel poll.
        if (w == 0) {
            if (lane == 0)
                __hip_atomic_store(&myflags[jt], tgt,
                                   __ATOMIC_RELAXED, __HIP_MEMORY_SCOPE_AGENT);
            for (;;) {
                unsigned v = __hip_atomic_load(&myflags[lane & 31],
                                               __ATOMIC_RELAXED, __HIP_MEMORY_SCOPE_AGENT);
                if (__all(v >= tgt)) break;
                __builtin_amdgcn_s_sleep(2);
            }
        }
        asm volatile("s_barrier" ::: "memory");
        __builtin_amdgcn_fence(__ATOMIC_ACQUIRE, "agent");  // inv stale cached h
        tgt += 1;
    };

    // ---- encoder: 168 steps (even count -> h_enc lands in slot 0) ----
    for (int t = 0; t < TD; ++t) {
        step(icb<true>{},
             hp + (size_t)(t & 1) * NH + ng * 32768,
             bje,
             hp + (size_t)((t + 1) & 1) * NH);
        bool more = (t + 1 < TD);
        if (more) loadX(t + 1);          // overlaps the barrier wait
        ngbar(more);
    }

    // ---- swap in decoder weights ----
    stageB(WdH, WdL, slabD, NCHD);
    __syncthreads();
    #pragma unroll
    for (int jj = 0; jj < 2; ++jj)
        #pragma unroll
        for (int r = 0; r < 4; ++r) cr[jj][r] = 0.f;

    // ---- decoder: 24 steps, outputs land in hs slots ----
    for (int s = 0; s < DSTEPS; ++s) {
        const unsigned* hb = ((s == 0) ? hp : hs + (size_t)(s - 1) * NH) + ng * 32768;
        step(icb<false>{}, hb, bjd, hs + (size_t)s * NH);
        ngbar(false);
    }
}

// ---------------------------------------------------------------------------
// Dense head over TILED hs: out[n][o][t] = sum_k unpack(hs) * Wd + bd.
// ---------------------------------------------------------------------------
__global__ __launch_bounds__(256)
void dense_kernel(const unsigned* __restrict__ hsP,
                  const float* __restrict__ Wd,
                  const float* __restrict__ bd,
                  float* __restrict__ out)
{
    const int t  = blockIdx.y;
    const int gx = blockIdx.x;          // n-group (n0 = gx*64)
    const int tid = threadIdx.x;
    const int to  = tid & 15;
    const int tn  = tid >> 4;

    __shared__ __align__(16) float aT[32 * 68];
    __shared__ __align__(16) float wT[32 * 68];

    float acc[4][4] = {};

    for (int ch = 0; ch < HD / 32; ++ch) {
        const int k0 = ch * 32;
        __syncthreads();
        #pragma unroll
        for (int i = 0; i < 8; ++i) {
            int e  = tid + i * 256;
            int kk = e & 31;
            int nl = e >> 5;
            int k  = k0 + kk;
            unsigned v = hsP[(size_t)t * (NB * HD)
                             + (size_t)(gx * 32 + (k >> 4)) * 1024 + nl * 16 + (k & 15)];
            aT[kk * 68 + nl] = bf2f((unsigned short)(v >> 16)) + bf2f((unsigned short)(v & 0xffffu));
            wT[kk * 68 + nl] = Wd[((size_t)t * OUTC + nl) * HD + k];
        }
        __syncthreads();
        #pragma unroll
        for (int kk = 0; kk < 32; ++kk) {
            float4 a = *reinterpret_cast<const float4*>(&aT[kk * 68 + tn * 4]);
            float4 wv = *reinterpret_cast<const float4*>(&wT[kk * 68 + to * 4]);
            acc[0][0] += a.x * wv.x; acc[0][1] += a.x * wv.y; acc[0][2] += a.x * wv.z; acc[0][3] += a.x * wv.w;
            acc[1][0] += a.y * wv.x; acc[1][1] += a.y * wv.y; acc[1][2] += a.y * wv.z; acc[1][3] += a.y * wv.w;
            acc[2][0] += a.z * wv.x; acc[2][1] += a.z * wv.y; acc[2][2] += a.z * wv.z; acc[2][3] += a.z * wv.w;
            acc[3][0] += a.w * wv.x; acc[3][1] += a.w * wv.y; acc[3][2] += a.w * wv.z; acc[3][3] += a.w * wv.w;
        }
    }

    #pragma unroll
    for (int i = 0; i < 4; ++i)
        #pragma unroll
        for (int jq = 0; jq < 4; ++jq) {
            int n = gx * 64 + tn * 4 + i;
            int o = to * 4 + jq;
            out[((size_t)n * OUTC + o) * DSTEPS + t] = acc[i][jq] + bd[t * OUTC + o];
        }
}

// ---------------------------------------------------------------------------
extern "C" void kernel_launch(void* const* d_in, const int* in_sizes, int n_in,
                              void* d_out, int out_size, void* d_ws, size_t ws_size,
                              hipStream_t stream) {
    const float* x       = (const float*)d_in[0];
    const float* W_ih_e  = (const float*)d_in[1];
    const float* W_hh_e  = (const float*)d_in[2];
    const float* b_e     = (const float*)d_in[3];
    const float* W_hh_d  = (const float*)d_in[4];
    const float* b_d     = (const float*)d_in[5];
    const float* W_dense = (const float*)d_in[6];
    const float* b_dense = (const float*)d_in[7];
    float* out = (float*)d_out;

    const size_t NH = (size_t)NB * HD;   // 262144 u32 elems

    char* pws = (char*)d_ws;
    auto alloc = [&](size_t bytes) { char* q = pws; pws += (bytes + 255) & ~(size_t)255; return q; };
    unsigned short* WeH = (unsigned short*)alloc((size_t)GATES * KWE * 2);
    unsigned short* WeL = (unsigned short*)alloc((size_t)GATES * KWE * 2);
    unsigned short* WdH = (unsigned short*)alloc((size_t)GATES * HD * 2);
    unsigned short* WdL = (unsigned short*)alloc((size_t)GATES * HD * 2);
    unsigned*       xTl = (unsigned*)alloc((size_t)TD * NB * CD * 4);
    unsigned*       hp  = (unsigned*)alloc(2 * NH * 4);
    unsigned*       hs  = (unsigned*)alloc((size_t)DSTEPS * NH * 4);
    unsigned*       flg = (unsigned*)alloc(8 * 32 * sizeof(unsigned));

    // Prep (every call; deterministic)
    prep_wfrag<<<dim3(32, NCHE), dim3(256), 0, stream>>>(W_hh_e, W_ih_e, WeH, WeL, NCHE);
    prep_wfrag<<<dim3(32, NCHD), dim3(256), 0, stream>>>(W_hh_d, W_hh_d, WdH, WdL, NCHD);
    prep_xT<<<dim3(NB), dim3(256), 0, stream>>>(x, xTl);

    (void)hipMemsetAsync(hp, 0, NH * 4, stream);                 // slot 0 = zeros
    (void)hipMemsetAsync(flg, 0, 8 * 32 * sizeof(unsigned), stream);

    lstm_persist<<<dim3(256), dim3(256), 0, stream>>>(
        WeH, WeL, WdH, WdL, xTl, b_e, b_d, hp, hs, flg);

    dense_kernel<<<dim3(NB / 64, DSTEPS), dim3(256), 0, stream>>>(
        hs, W_dense, b_dense, out);
}

// Round 14
// 2030.946 us; speedup vs baseline: 2.4116x; 1.4972x over previous
//
#include <hip/hip_runtime.h>
#include <math.h>
#include <type_traits>

// Problem constants
#define NB 512     // batch
#define HD 512     // hidden
#define CD 64      // in channels
#define TD 168     // encode length
#define DSTEPS 24  // decoder steps
#define OUTC 64    // out channels
#define GATES 2048 // 4*HD
#define KWE (HD + CD)   // encoder K = 576
#define NCHE 18         // encoder K chunks (32 each)
#define NCHD 16         // decoder K chunks
#define NBLDS 17        // B chunks in LDS (encoder chunk 17 in regs on q=1 waves)

typedef short bf16x8 __attribute__((ext_vector_type(8)));
typedef float f32x4 __attribute__((ext_vector_type(4)));
typedef unsigned u32x4 __attribute__((ext_vector_type(4)));

template<bool B> using icb = std::integral_constant<bool, B>;

// Counted wait + scheduler fence (rule #18: hipcc hoists reg-only MFMA past
// inline-asm waitcnt; sched_barrier(0) right after is the required fence).
#define WAITV(N) do { asm volatile("s_waitcnt vmcnt(" #N ")" ::: "memory"); \
                      __builtin_amdgcn_sched_barrier(0); } while (0)

__device__ __forceinline__ float sigmf(float x) { return 1.0f / (1.0f + expf(-x)); }
__device__ __forceinline__ float bf2f(unsigned short h) {
    return __uint_as_float(((unsigned)h) << 16);
}
__device__ __forceinline__ unsigned short f2bf(float x) {  // round-to-nearest-even
    unsigned u = __float_as_uint(x);
    return (unsigned short)((u + 0x7fffu + ((u >> 16) & 1u)) >> 16);
}
__device__ __forceinline__ unsigned packsplit(float v) {   // bf16 hi|lo packed
    unsigned short hi = f2bf(v);
    unsigned short lo = f2bf(v - bf2f(hi));
    return ((unsigned)hi << 16) | (unsigned)lo;
}

// Build hi/lo bf16x8 fragments from 8 packed (hi<<16|lo) words via v_perm.
__device__ __forceinline__ void mkfrag(u32x4 a, u32x4 b, bf16x8& hi, bf16x8& lo) {
    u32x4 h, l;
    h.x = __builtin_amdgcn_perm(a.y, a.x, 0x07060302u);
    h.y = __builtin_amdgcn_perm(a.w, a.z, 0x07060302u);
    h.z = __builtin_amdgcn_perm(b.y, b.x, 0x07060302u);
    h.w = __builtin_amdgcn_perm(b.w, b.z, 0x07060302u);
    l.x = __builtin_amdgcn_perm(a.y, a.x, 0x05040100u);
    l.y = __builtin_amdgcn_perm(a.w, a.z, 0x05040100u);
    l.z = __builtin_amdgcn_perm(b.y, b.x, 0x05040100u);
    l.w = __builtin_amdgcn_perm(b.w, b.z, 0x05040100u);
    hi = *(bf16x8*)&h;
    lo = *(bf16x8*)&l;
}

// h loads: SYSTEM-scope (sc0 sc1 = bypass L1+L2, read MALL). The h stores are
// sc0 sc1 write-through + vmcnt-drained before the flag publishes, so a MALL
// read after seeing the flag is coherent WITHOUT any L2-invalidate fence.
__device__ __forceinline__ void ld2g_sys(const unsigned* p, u32x4& a, u32x4& b) {
    asm volatile("global_load_dwordx4 %0, %2, off sc0 sc1\n\t"
                 "global_load_dwordx4 %1, %2, off offset:16 sc0 sc1"
                 : "=&v"(a), "=&v"(b) : "v"(p) : "memory");
}
// x loads: plain cached (x is read-only; no staleness possible). Still asm so
// the vmcnt ladder accounting stays exact.
__device__ __forceinline__ void ld2g_x(const unsigned* p, u32x4& a, u32x4& b) {
    asm volatile("global_load_dwordx4 %0, %2, off\n\t"
                 "global_load_dwordx4 %1, %2, off offset:16"
                 : "=&v"(a), "=&v"(b) : "v"(p));
}

// ---------------------------------------------------------------------------
// Weight prep: bf16 hi/lo planes, permuted + fragment-ready.
// Elem [(ch*4+ks)*64 + gc][m] holds source row gate*HD + jt*16 + jj at
// k = ch*32 + ks*8 + m, with gate=(gc>>3)&3, jj=(gc&7)+8*(gc>>5).
// ---------------------------------------------------------------------------
__global__ __launch_bounds__(256)
void prep_wfrag(const float* __restrict__ Whh, const float* __restrict__ Wih,
                unsigned short* __restrict__ Ph, unsigned short* __restrict__ Pl,
                int nch)
{
    const int jt = blockIdx.x, ch = blockIdx.y;
    const int ks = threadIdx.x >> 6, gc = threadIdx.x & 63;
    const int gate = (gc >> 3) & 3;
    const int jj = (gc & 7) + ((gc >> 5) << 3);
    const int srow = gate * HD + jt * 16 + jj;
    const int k0 = ch * 32 + ks * 8;
    const size_t o = (size_t)jt * (64 * nch * 32) + (size_t)((ch * 4 + ks) * 64 + gc) * 8;
    #pragma unroll
    for (int m = 0; m < 8; ++m) {
        int k = k0 + m;
        float v = (k < HD) ? Whh[(size_t)srow * HD + k] : Wih[(size_t)srow * CD + (k - HD)];
        unsigned short hi = f2bf(v);
        Ph[o + m] = hi;
        Pl[o + m] = f2bf(v - bf2f(hi));
    }
}

// ---------------------------------------------------------------------------
// x prep: (N,C,T) f32 -> packed u32, TILED: xT[t][ng][ct][64][16].
// ---------------------------------------------------------------------------
__global__ __launch_bounds__(256)
void prep_xT(const float* __restrict__ x, unsigned* __restrict__ Xt)
{
    __shared__ float tile[CD * TD];
    const int n = blockIdx.x;
    for (int e = threadIdx.x; e < CD * TD; e += 256)
        tile[e] = x[(size_t)n * CD * TD + e];
    __syncthreads();
    for (int e = threadIdx.x; e < CD * TD; e += 256) {
        int t = e >> 6, c = e & 63;
        size_t o = ((size_t)(t * 8 + (n >> 6)) * 4 + (c >> 4)) * 1024 + (n & 63) * 16 + (c & 15);
        Xt[o] = packsplit(tile[c * TD + t]);
    }
}

// ---------------------------------------------------------------------------
// Persistent encoder+decoder. 256 blocks x 256 threads (4 waves), 1 block/CU.
// r13 base EXCEPT fence-free coherence: h loads are system-scope (sc0 sc1,
// read MALL directly), so the per-step agent acquire-fence (full L2
// invalidate) and the wave0-relay second barrier are GONE. Every wave polls
// the 32 arrival flags independently and proceeds as soon as they land.
// ---------------------------------------------------------------------------
__global__ __launch_bounds__(256, 1)
void lstm_persist(const unsigned short* __restrict__ WeH, const unsigned short* __restrict__ WeL,
                  const unsigned short* __restrict__ WdH, const unsigned short* __restrict__ WdL,
                  const unsigned* __restrict__ xT,
                  const float* __restrict__ b_e, const float* __restrict__ b_d,
                  unsigned* __restrict__ hp,   // [2][NB*HD] packed, tiled
                  unsigned* __restrict__ hs,   // [DSTEPS][NB*HD] packed, tiled
                  unsigned* __restrict__ flags)
{
    __shared__ __align__(16) unsigned short BhS[NBLDS * 2048];  // 69632 B
    __shared__ __align__(16) unsigned short BlS[NBLDS * 2048];  // 69632 B
    __shared__ __align__(16) float red[4 * 1280];               // 20480 B

    const int tid  = threadIdx.x;
    const int lane = tid & 63;
    const int w    = tid >> 6;          // wave 0..3
    const int p2   = w >> 1;            // fm-pair (rows p2*32..+31)
    const int q    = w & 1;             // chunk parity
    const int jt   = blockIdx.x >> 3;   // 0..31
    const int ng   = blockIdx.x & 7;    // n-group (== XCD heuristic, perf only)

    const int rs    = lane >> 4;        // frag k-slot 0..3
    const int c15   = lane & 15;
    const int pl    = (lane >> 3) & 1;
    const int jbase = jt * 16 + (lane & 7);
    const int rowcol0 = (p2 * 32 + c15) * 16 + (rs & 1) * 8;        // fmL=0
    const int rowcol1 = (p2 * 32 + 16 + c15) * 16 + (rs & 1) * 8;   // fmL=1
    const int tsub    = rs >> 1;        // which of the chunk's 2 tiles

    const size_t slabE = (size_t)jt * (64 * KWE);
    const size_t slabD = (size_t)jt * (64 * HD);
    const size_t NH    = (size_t)NB * HD;   // u32 elems per h buffer

    // Biases
    float bje[2][4], bjd[2][4];
    #pragma unroll
    for (int g = 0; g < 4; ++g) {
        bje[0][g] = b_e[g * HD + jbase];
        bje[1][g] = b_e[g * HD + jbase + 8];
        bjd[0][g] = b_d[g * HD + jbase];
        bjd[1][g] = b_d[g * HD + jbase + 8];
    }

    auto stageB = [&](const unsigned short* PH, const unsigned short* PL,
                      size_t slab, int nchunks) {
        for (int e = tid; e < nchunks * 256; e += 256) {
            *(bf16x8*)&BhS[(size_t)e * 8] = *(const bf16x8*)&PH[slab + (size_t)e * 8];
            *(bf16x8*)&BlS[(size_t)e * 8] = *(const bf16x8*)&PL[slab + (size_t)e * 8];
        }
    };
    // Encoder tail B chunk (17) in regs on q==1 waves.
    bf16x8 tbh[4], tbl[4];
    if (q == 1) {
        #pragma unroll
        for (int fg = 0; fg < 4; ++fg) {
            size_t o = slabE + (size_t)((17 * 4 + rs) * 64 + fg * 16 + c15) * 8;
            tbh[fg] = *(const bf16x8*)&WeH[o];
            tbl[fg] = *(const bf16x8*)&WeL[o];
        }
    }
    stageB(WeH, WeL, slabE, NBLDS);

    // x prefetch regs (chunk 16 for q=0, 17 for q=1)
    u32x4 xpend[4];
    auto loadX = [&](int t) {
        const unsigned* xb = xT + (size_t)((t * 8 + ng) * 4) * 1024;
        ld2g_x(xb + (q * 2 + tsub) * 1024 + rowcol0, xpend[0], xpend[1]);
        ld2g_x(xb + (q * 2 + tsub) * 1024 + rowcol1, xpend[2], xpend[3]);
    };
    loadX(0);
    asm volatile("s_waitcnt vmcnt(0)" ::: "memory");
    __syncthreads();

    float cr[2][4] = {};                 // cell state [jjhi][r]
    unsigned tgt = 1;                    // monotonic step id (flag value)
    unsigned* myflags = &flags[ng * 32];

    auto step = [&](auto HASXC,
                    const unsigned* __restrict__ hb,    // ng-offset tiled h src
                    const float (&bj)[2][4],
                    unsigned* __restrict__ hdst)        // full tiled base
    {
        constexpr bool HASX = decltype(HASXC)::value;
        f32x4 acc[2][4] = {};            // [fmL][fg]
        u32x4 pd[8][4];

        // Issue ALL 32 h loads now (asm: cannot be sunk).
        #pragma unroll
        for (int i = 0; i < 8; ++i) {
            const int ch = q + 2 * i;
            ld2g_sys(hb + (2 * ch + tsub) * 1024 + rowcol0, pd[i][0], pd[i][1]);
            ld2g_sys(hb + (2 * ch + tsub) * 1024 + rowcol1, pd[i][2], pd[i][3]);
        }

        // x chunk FIRST: x regs are already complete (drained in the poll),
        // compute while h flies. WAITV(32) is a cheap no-op guard.
        if constexpr (HASX) {
            WAITV(32);
            bf16x8 bh[4], bl[4];
            if (q == 0) {
                #pragma unroll
                for (int fg = 0; fg < 4; ++fg) {
                    const int bi = ((16 * 4 + rs) * 64 + fg * 16 + c15) * 8;
                    bh[fg] = *(const bf16x8*)&BhS[bi];
                    bl[fg] = *(const bf16x8*)&BlS[bi];
                }
            } else {
                #pragma unroll
                for (int fg = 0; fg < 4; ++fg) { bh[fg] = tbh[fg]; bl[fg] = tbl[fg]; }
            }
            bf16x8 ah0, al0, ah1, al1;
            mkfrag(xpend[0], xpend[1], ah0, al0);
            mkfrag(xpend[2], xpend[3], ah1, al1);
            #pragma unroll
            for (int fg = 0; fg < 4; ++fg) {
                acc[0][fg] = __builtin_amdgcn_mfma_f32_16x16x32_bf16(ah0, bh[fg], acc[0][fg], 0, 0, 0);
                acc[0][fg] = __builtin_amdgcn_mfma_f32_16x16x32_bf16(ah0, bl[fg], acc[0][fg], 0, 0, 0);
                acc[0][fg] = __builtin_amdgcn_mfma_f32_16x16x32_bf16(al0, bh[fg], acc[0][fg], 0, 0, 0);
                acc[1][fg] = __builtin_amdgcn_mfma_f32_16x16x32_bf16(ah1, bh[fg], acc[1][fg], 0, 0, 0);
                acc[1][fg] = __builtin_amdgcn_mfma_f32_16x16x32_bf16(ah1, bl[fg], acc[1][fg], 0, 0, 0);
                acc[1][fg] = __builtin_amdgcn_mfma_f32_16x16x32_bf16(al1, bh[fg], acc[1][fg], 0, 0, 0);
            }
        }

        // K-loop: counted vmcnt ladder releases one chunk at a time.
        #pragma unroll
        for (int i = 0; i < 8; ++i) {
            if      (i == 0) WAITV(28);
            else if (i == 1) WAITV(24);
            else if (i == 2) WAITV(20);
            else if (i == 3) WAITV(16);
            else if (i == 4) WAITV(12);
            else if (i == 5) WAITV(8);
            else if (i == 6) WAITV(4);
            else             WAITV(0);

            const int ch = q + 2 * i;
            bf16x8 bh[4], bl[4];
            #pragma unroll
            for (int fg = 0; fg < 4; ++fg) {
                const int bi = ((ch * 4 + rs) * 64 + fg * 16 + c15) * 8;
                bh[fg] = *(const bf16x8*)&BhS[bi];
                bl[fg] = *(const bf16x8*)&BlS[bi];
            }
            bf16x8 ah0, al0, ah1, al1;
            mkfrag(pd[i][0], pd[i][1], ah0, al0);
            mkfrag(pd[i][2], pd[i][3], ah1, al1);
            #pragma unroll
            for (int fg = 0; fg < 4; ++fg) {
                acc[0][fg] = __builtin_amdgcn_mfma_f32_16x16x32_bf16(ah0, bh[fg], acc[0][fg], 0, 0, 0);
                acc[0][fg] = __builtin_amdgcn_mfma_f32_16x16x32_bf16(ah0, bl[fg], acc[0][fg], 0, 0, 0);
                acc[0][fg] = __builtin_amdgcn_mfma_f32_16x16x32_bf16(al0, bh[fg], acc[0][fg], 0, 0, 0);
                acc[1][fg] = __builtin_amdgcn_mfma_f32_16x16x32_bf16(ah1, bh[fg], acc[1][fg], 0, 0, 0);
                acc[1][fg] = __builtin_amdgcn_mfma_f32_16x16x32_bf16(ah1, bl[fg], acc[1][fg], 0, 0, 0);
                acc[1][fg] = __builtin_amdgcn_mfma_f32_16x16x32_bf16(al1, bh[fg], acc[1][fg], 0, 0, 0);
            }
        }

        // Partner reduction: wave w keeps fm = w (static acc indexing only).
        f32x4 keep[4], give[4];
        if (q == 0) {
            #pragma unroll
            for (int fg = 0; fg < 4; ++fg) { keep[fg] = acc[0][fg]; give[fg] = acc[1][fg]; }
        } else {
            #pragma unroll
            for (int fg = 0; fg < 4; ++fg) { keep[fg] = acc[1][fg]; give[fg] = acc[0][fg]; }
        }
        float* myslot = &red[w * 1280 + lane * 20];
        #pragma unroll
        for (int fg = 0; fg < 4; ++fg) *(f32x4*)&myslot[fg * 4] = give[fg];
        __syncthreads();
        const float* ps = &red[(w ^ 1) * 1280 + lane * 20];
        #pragma unroll
        for (int fg = 0; fg < 4; ++fg) keep[fg] += *(const f32x4*)&ps[fg * 4];
        __syncthreads();                 // red free -> otile overlay safe

        // Epilogue -> LDS out-tile (4KB), then coalesced sc1 store.
        unsigned* otile = (unsigned*)red;
        #pragma unroll
        for (int r = 0; r < 4; ++r) {
            float v0 = keep[0][r], v1 = keep[1][r];
            float v2 = keep[2][r], v3 = keep[3][r];
            float u0 = __shfl_xor(v0, 8, 64);
            float u1 = __shfl_xor(v1, 8, 64);
            float u2 = __shfl_xor(v2, 8, 64);
            float u3 = __shfl_xor(v3, 8, 64);
            if (pl == 0) {
                const int row = w * 16 + (lane >> 4) * 4 + r;
                {
                    float gi = v0 + bj[0][0], gf = u0 + bj[0][1];
                    float gg = v1 + bj[0][2], go = u1 + bj[0][3];
                    float cn = sigmf(gf) * cr[0][r] + sigmf(gi) * tanhf(gg);
                    float hn = sigmf(go) * tanhf(cn);
                    cr[0][r] = cn;
                    otile[row * 16 + (lane & 7)] = packsplit(hn);
                }
                {
                    float gi = v2 + bj[1][0], gf = u2 + bj[1][1];
                    float gg = v3 + bj[1][2], go = u3 + bj[1][3];
                    float cn = sigmf(gf) * cr[1][r] + sigmf(gi) * tanhf(gg);
                    float hn = sigmf(go) * tanhf(cn);
                    cr[1][r] = cn;
                    otile[row * 16 + (lane & 7) + 8] = packsplit(hn);
                }
            }
        }
        __syncthreads();
        u32x4 hv = *(const u32x4*)&otile[tid * 4];
        unsigned* dst = hdst + (size_t)(ng * 32 + jt) * 1024 + tid * 4;
        asm volatile("global_store_dwordx4 %0, %1, off sc0 sc1"
                     :: "v"(dst), "v"(hv) : "memory");
    };

    auto ngbar = [&]() {
        // Drain everything (h store reaches MALL; x prefetch also retires —
        // the atomic poll would drain it anyway), one intra-block barrier so
        // the flag covers all 4 waves' stores, then publish + per-wave poll.
        asm volatile("s_waitcnt vmcnt(0) lgkmcnt(0)" ::: "memory");
        asm volatile("s_barrier" ::: "memory");
        if (tid == 0)
            __hip_atomic_store(&myflags[jt], tgt,
                               __ATOMIC_RELAXED, __HIP_MEMORY_SCOPE_AGENT);
        // EVERY wave polls independently: no relay barrier, no fence. The
        // next step's h reads are system-scope so no invalidate is needed.
        for (;;) {
            unsigned v = __hip_atomic_load(&myflags[lane & 31],
                                           __ATOMIC_RELAXED, __HIP_MEMORY_SCOPE_AGENT);
            if (__all(v >= tgt)) break;
            __builtin_amdgcn_s_sleep(1);
        }
        __builtin_amdgcn_sched_barrier(0);   // pin subsequent h loads after poll
        tgt += 1;
    };

    // ---- encoder: 168 steps (even count -> h_enc lands in slot 0) ----
    for (int t = 0; t < TD; ++t) {
        step(icb<true>{},
             hp + (size_t)(t & 1) * NH + ng * 32768,
             bje,
             hp + (size_t)((t + 1) & 1) * NH);
        if (t + 1 < TD) loadX(t + 1);    // overlaps the drain + poll
        ngbar();
    }

    // ---- swap in decoder weights ----
    stageB(WdH, WdL, slabD, NCHD);
    __syncthreads();
    #pragma unroll
    for (int jj = 0; jj < 2; ++jj)
        #pragma unroll
        for (int r = 0; r < 4; ++r) cr[jj][r] = 0.f;

    // ---- decoder: 24 steps, outputs land in hs slots ----
    for (int s = 0; s < DSTEPS; ++s) {
        const unsigned* hb = ((s == 0) ? hp : hs + (size_t)(s - 1) * NH) + ng * 32768;
        step(icb<false>{}, hb, bjd, hs + (size_t)s * NH);
        ngbar();
    }
}

// ---------------------------------------------------------------------------
// Dense head over TILED hs: out[n][o][t] = sum_k unpack(hs) * Wd + bd.
// (Separate dispatch: kernel boundary provides system coherence for hs.)
// ---------------------------------------------------------------------------
__global__ __launch_bounds__(256)
void dense_kernel(const unsigned* __restrict__ hsP,
                  const float* __restrict__ Wd,
                  const float* __restrict__ bd,
                  float* __restrict__ out)
{
    const int t  = blockIdx.y;
    const int gx = blockIdx.x;          // n-group (n0 = gx*64)
    const int tid = threadIdx.x;
    const int to  = tid & 15;
    const int tn  = tid >> 4;

    __shared__ __align__(16) float aT[32 * 68];
    __shared__ __align__(16) float wT[32 * 68];

    float acc[4][4] = {};

    for (int ch = 0; ch < HD / 32; ++ch) {
        const int k0 = ch * 32;
        __syncthreads();
        #pragma unroll
        for (int i = 0; i < 8; ++i) {
            int e  = tid + i * 256;
            int kk = e & 31;
            int nl = e >> 5;
            int k  = k0 + kk;
            unsigned v = hsP[(size_t)t * (NB * HD)
                             + (size_t)(gx * 32 + (k >> 4)) * 1024 + nl * 16 + (k & 15)];
            aT[kk * 68 + nl] = bf2f((unsigned short)(v >> 16)) + bf2f((unsigned short)(v & 0xffffu));
            wT[kk * 68 + nl] = Wd[((size_t)t * OUTC + nl) * HD + k];
        }
        __syncthreads();
        #pragma unroll
        for (int kk = 0; kk < 32; ++kk) {
            float4 a = *reinterpret_cast<const float4*>(&aT[kk * 68 + tn * 4]);
            float4 wv = *reinterpret_cast<const float4*>(&wT[kk * 68 + to * 4]);
            acc[0][0] += a.x * wv.x; acc[0][1] += a.x * wv.y; acc[0][2] += a.x * wv.z; acc[0][3] += a.x * wv.w;
            acc[1][0] += a.y * wv.x; acc[1][1] += a.y * wv.y; acc[1][2] += a.y * wv.z; acc[1][3] += a.y * wv.w;
            acc[2][0] += a.z * wv.x; acc[2][1] += a.z * wv.y; acc[2][2] += a.z * wv.z; acc[2][3] += a.z * wv.w;
            acc[3][0] += a.w * wv.x; acc[3][1] += a.w * wv.y; acc[3][2] += a.w * wv.z; acc[3][3] += a.w * wv.w;
        }
    }

    #pragma unroll
    for (int i = 0; i < 4; ++i)
        #pragma unroll
        for (int jq = 0; jq < 4; ++jq) {
            int n = gx * 64 + tn * 4 + i;
            int o = to * 4 + jq;
            out[((size_t)n * OUTC + o) * DSTEPS + t] = acc[i][jq] + bd[t * OUTC + o];
        }
}

// ---------------------------------------------------------------------------
extern "C" void kernel_launch(void* const* d_in, const int* in_sizes, int n_in,
                              void* d_out, int out_size, void* d_ws, size_t ws_size,
                              hipStream_t stream) {
    const float* x       = (const float*)d_in[0];
    const float* W_ih_e  = (const float*)d_in[1];
    const float* W_hh_e  = (const float*)d_in[2];
    const float* b_e     = (const float*)d_in[3];
    const float* W_hh_d  = (const float*)d_in[4];
    const float* b_d     = (const float*)d_in[5];
    const float* W_dense = (const float*)d_in[6];
    const float* b_dense = (const float*)d_in[7];
    float* out = (float*)d_out;

    const size_t NH = (size_t)NB * HD;   // 262144 u32 elems

    char* pws = (char*)d_ws;
    auto alloc = [&](size_t bytes) { char* q = pws; pws += (bytes + 255) & ~(size_t)255; return q; };
    unsigned short* WeH = (unsigned short*)alloc((size_t)GATES * KWE * 2);
    unsigned short* WeL = (unsigned short*)alloc((size_t)GATES * KWE * 2);
    unsigned short* WdH = (unsigned short*)alloc((size_t)GATES * HD * 2);
    unsigned short* WdL = (unsigned short*)alloc((size_t)GATES * HD * 2);
    unsigned*       xTl = (unsigned*)alloc((size_t)TD * NB * CD * 4);
    unsigned*       hp  = (unsigned*)alloc(2 * NH * 4);
    unsigned*       hs  = (unsigned*)alloc((size_t)DSTEPS * NH * 4);
    unsigned*       flg = (unsigned*)alloc(8 * 32 * sizeof(unsigned));

    // Prep (every call; deterministic)
    prep_wfrag<<<dim3(32, NCHE), dim3(256), 0, stream>>>(W_hh_e, W_ih_e, WeH, WeL, NCHE);
    prep_wfrag<<<dim3(32, NCHD), dim3(256), 0, stream>>>(W_hh_d, W_hh_d, WdH, WdL, NCHD);
    prep_xT<<<dim3(NB), dim3(256), 0, stream>>>(x, xTl);

    (void)hipMemsetAsync(hp, 0, NH * 4, stream);                 // slot 0 = zeros
    (void)hipMemsetAsync(flg, 0, 8 * 32 * sizeof(unsigned), stream);

    lstm_persist<<<dim3(256), dim3(256), 0, stream>>>(
        WeH, WeL, WdH, WdL, xTl, b_e, b_d, hp, hs, flg);

    dense_kernel<<<dim3(NB / 64, DSTEPS), dim3(256), 0, stream>>>(
        hs, W_dense, b_dense, out);
}

// Round 15
// 1666.950 us; speedup vs baseline: 2.9382x; 1.2184x over previous
//
#include <hip/hip_runtime.h>
#include <math.h>
#include <type_traits>

// Problem constants
#define NB 512     // batch
#define HD 512     // hidden
#define CD 64      // in channels
#define TD 168     // encode length
#define DSTEPS 24  // decoder steps
#define OUTC 64    // out channels
#define GATES 2048 // 4*HD
#define KWE (HD + CD)   // encoder K = 576
#define NCHE 18         // encoder K chunks (32 each)
#define NCHD 16         // decoder K chunks
#define NBLDS 17        // B chunks in LDS (encoder chunk 17 in regs on q=1 waves)

typedef short bf16x8 __attribute__((ext_vector_type(8)));
typedef float f32x4 __attribute__((ext_vector_type(4)));
typedef unsigned u32x4 __attribute__((ext_vector_type(4)));

template<bool B> using icb = std::integral_constant<bool, B>;

// Counted wait + scheduler fence (rule #18: hipcc hoists reg-only MFMA past
// inline-asm waitcnt; sched_barrier(0) right after is the required fence).
#define WAITV(N) do { asm volatile("s_waitcnt vmcnt(" #N ")" ::: "memory"); \
                      __builtin_amdgcn_sched_barrier(0); } while (0)

// Fast gate nonlinearities via v_exp_f32 (2^x) + v_rcp_f32 (~1 ulp each —
// negligible vs the bf16x3 path's 2.4e-4 absmax). Saturation is exact:
// exp2(+inf)=inf -> rcp=0; exp2(-inf)=0.
__device__ __forceinline__ float rcpf(float x) { return __builtin_amdgcn_rcpf(x); }
__device__ __forceinline__ float sigmf(float x) {
    return rcpf(1.0f + __builtin_amdgcn_exp2f(-1.442695040888963f * x));
}
__device__ __forceinline__ float tanh_fast(float x) {
    return 1.0f - 2.0f * rcpf(1.0f + __builtin_amdgcn_exp2f(2.885390081777926f * x));
}

__device__ __forceinline__ float bf2f(unsigned short h) {
    return __uint_as_float(((unsigned)h) << 16);
}
__device__ __forceinline__ unsigned short f2bf(float x) {  // round-to-nearest-even
    unsigned u = __float_as_uint(x);
    return (unsigned short)((u + 0x7fffu + ((u >> 16) & 1u)) >> 16);
}
__device__ __forceinline__ unsigned packsplit(float v) {   // bf16 hi|lo packed
    unsigned short hi = f2bf(v);
    unsigned short lo = f2bf(v - bf2f(hi));
    return ((unsigned)hi << 16) | (unsigned)lo;
}

// Build hi/lo bf16x8 fragments from 8 packed (hi<<16|lo) words via v_perm.
__device__ __forceinline__ void mkfrag(u32x4 a, u32x4 b, bf16x8& hi, bf16x8& lo) {
    u32x4 h, l;
    h.x = __builtin_amdgcn_perm(a.y, a.x, 0x07060302u);
    h.y = __builtin_amdgcn_perm(a.w, a.z, 0x07060302u);
    h.z = __builtin_amdgcn_perm(b.y, b.x, 0x07060302u);
    h.w = __builtin_amdgcn_perm(b.w, b.z, 0x07060302u);
    l.x = __builtin_amdgcn_perm(a.y, a.x, 0x05040100u);
    l.y = __builtin_amdgcn_perm(a.w, a.z, 0x05040100u);
    l.z = __builtin_amdgcn_perm(b.y, b.x, 0x05040100u);
    l.w = __builtin_amdgcn_perm(b.w, b.z, 0x05040100u);
    hi = *(bf16x8*)&h;
    lo = *(bf16x8*)&l;
}

// h loads: SYSTEM-scope (sc0 sc1 = bypass L1+L2, read MALL). The h stores are
// sc0 sc1 write-through + vmcnt-drained before the flag publishes, so a MALL
// read after seeing the flag is coherent WITHOUT any L2-invalidate fence.
__device__ __forceinline__ void ld2g_sys(const unsigned* p, u32x4& a, u32x4& b) {
    asm volatile("global_load_dwordx4 %0, %2, off sc0 sc1\n\t"
                 "global_load_dwordx4 %1, %2, off offset:16 sc0 sc1"
                 : "=&v"(a), "=&v"(b) : "v"(p) : "memory");
}
// x loads: plain cached (x is read-only; no staleness possible). Still asm so
// the vmcnt ladder accounting stays exact.
__device__ __forceinline__ void ld2g_x(const unsigned* p, u32x4& a, u32x4& b) {
    asm volatile("global_load_dwordx4 %0, %2, off\n\t"
                 "global_load_dwordx4 %1, %2, off offset:16"
                 : "=&v"(a), "=&v"(b) : "v"(p));
}
// Scattered epilogue h store (system-scope, packed u32).
__device__ __forceinline__ void st_sys(unsigned* p, unsigned v) {
    asm volatile("global_store_dword %0, %1, off sc0 sc1"
                 :: "v"(p), "v"(v) : "memory");
}

// ---------------------------------------------------------------------------
// Weight prep: bf16 hi/lo planes, permuted + fragment-ready.
// Elem [(ch*4+ks)*64 + gc][m] holds source row gate*HD + jt*16 + jj at
// k = ch*32 + ks*8 + m, with gate=(gc>>3)&3, jj=(gc&7)+8*(gc>>5).
// ---------------------------------------------------------------------------
__global__ __launch_bounds__(256)
void prep_wfrag(const float* __restrict__ Whh, const float* __restrict__ Wih,
                unsigned short* __restrict__ Ph, unsigned short* __restrict__ Pl,
                int nch)
{
    const int jt = blockIdx.x, ch = blockIdx.y;
    const int ks = threadIdx.x >> 6, gc = threadIdx.x & 63;
    const int gate = (gc >> 3) & 3;
    const int jj = (gc & 7) + ((gc >> 5) << 3);
    const int srow = gate * HD + jt * 16 + jj;
    const int k0 = ch * 32 + ks * 8;
    const size_t o = (size_t)jt * (64 * nch * 32) + (size_t)((ch * 4 + ks) * 64 + gc) * 8;
    #pragma unroll
    for (int m = 0; m < 8; ++m) {
        int k = k0 + m;
        float v = (k < HD) ? Whh[(size_t)srow * HD + k] : Wih[(size_t)srow * CD + (k - HD)];
        unsigned short hi = f2bf(v);
        Ph[o + m] = hi;
        Pl[o + m] = f2bf(v - bf2f(hi));
    }
}

// ---------------------------------------------------------------------------
// x prep: (N,C,T) f32 -> packed u32, TILED: xT[t][ng][ct][64][16].
// ---------------------------------------------------------------------------
__global__ __launch_bounds__(256)
void prep_xT(const float* __restrict__ x, unsigned* __restrict__ Xt)
{
    __shared__ float tile[CD * TD];
    const int n = blockIdx.x;
    for (int e = threadIdx.x; e < CD * TD; e += 256)
        tile[e] = x[(size_t)n * CD * TD + e];
    __syncthreads();
    for (int e = threadIdx.x; e < CD * TD; e += 256) {
        int t = e >> 6, c = e & 63;
        size_t o = ((size_t)(t * 8 + (n >> 6)) * 4 + (c >> 4)) * 1024 + (n & 63) * 16 + (c & 15);
        Xt[o] = packsplit(tile[c * TD + t]);
    }
}

// ---------------------------------------------------------------------------
// Persistent encoder+decoder. 256 blocks x 256 threads (4 waves), 1 block/CU.
// r14 base (fence-free system-scope h exchange) with: fast exp2-based gate
// nonlinearities, direct scattered epilogue stores (no LDS otile repack,
// 2 fewer barriers/step), post-reduction barrier folded into ngbar's.
// ---------------------------------------------------------------------------
__global__ __launch_bounds__(256, 1)
void lstm_persist(const unsigned short* __restrict__ WeH, const unsigned short* __restrict__ WeL,
                  const unsigned short* __restrict__ WdH, const unsigned short* __restrict__ WdL,
                  const unsigned* __restrict__ xT,
                  const float* __restrict__ b_e, const float* __restrict__ b_d,
                  unsigned* __restrict__ hp,   // [2][NB*HD] packed, tiled
                  unsigned* __restrict__ hs,   // [DSTEPS][NB*HD] packed, tiled
                  unsigned* __restrict__ flags)
{
    __shared__ __align__(16) unsigned short BhS[NBLDS * 2048];  // 69632 B
    __shared__ __align__(16) unsigned short BlS[NBLDS * 2048];  // 69632 B
    __shared__ __align__(16) float red[4 * 1280];               // 20480 B

    const int tid  = threadIdx.x;
    const int lane = tid & 63;
    const int w    = tid >> 6;          // wave 0..3
    const int p2   = w >> 1;            // fm-pair (rows p2*32..+31)
    const int q    = w & 1;             // chunk parity
    const int jt   = blockIdx.x >> 3;   // 0..31
    const int ng   = blockIdx.x & 7;    // n-group (== XCD heuristic, perf only)

    const int rs    = lane >> 4;        // frag k-slot 0..3
    const int c15   = lane & 15;
    const int pl    = (lane >> 3) & 1;
    const int jbase = jt * 16 + (lane & 7);
    const int rowcol0 = (p2 * 32 + c15) * 16 + (rs & 1) * 8;        // fmL=0
    const int rowcol1 = (p2 * 32 + 16 + c15) * 16 + (rs & 1) * 8;   // fmL=1
    const int tsub    = rs >> 1;        // which of the chunk's 2 tiles

    const size_t slabE = (size_t)jt * (64 * KWE);
    const size_t slabD = (size_t)jt * (64 * HD);
    const size_t NH    = (size_t)NB * HD;   // u32 elems per h buffer

    // Biases
    float bje[2][4], bjd[2][4];
    #pragma unroll
    for (int g = 0; g < 4; ++g) {
        bje[0][g] = b_e[g * HD + jbase];
        bje[1][g] = b_e[g * HD + jbase + 8];
        bjd[0][g] = b_d[g * HD + jbase];
        bjd[1][g] = b_d[g * HD + jbase + 8];
    }

    auto stageB = [&](const unsigned short* PH, const unsigned short* PL,
                      size_t slab, int nchunks) {
        for (int e = tid; e < nchunks * 256; e += 256) {
            *(bf16x8*)&BhS[(size_t)e * 8] = *(const bf16x8*)&PH[slab + (size_t)e * 8];
            *(bf16x8*)&BlS[(size_t)e * 8] = *(const bf16x8*)&PL[slab + (size_t)e * 8];
        }
    };
    // Encoder tail B chunk (17) in regs on q==1 waves.
    bf16x8 tbh[4], tbl[4];
    if (q == 1) {
        #pragma unroll
        for (int fg = 0; fg < 4; ++fg) {
            size_t o = slabE + (size_t)((17 * 4 + rs) * 64 + fg * 16 + c15) * 8;
            tbh[fg] = *(const bf16x8*)&WeH[o];
            tbl[fg] = *(const bf16x8*)&WeL[o];
        }
    }
    stageB(WeH, WeL, slabE, NBLDS);

    // x prefetch regs (chunk 16 for q=0, 17 for q=1)
    u32x4 xpend[4];
    auto loadX = [&](int t) {
        const unsigned* xb = xT + (size_t)((t * 8 + ng) * 4) * 1024;
        ld2g_x(xb + (q * 2 + tsub) * 1024 + rowcol0, xpend[0], xpend[1]);
        ld2g_x(xb + (q * 2 + tsub) * 1024 + rowcol1, xpend[2], xpend[3]);
    };
    loadX(0);
    asm volatile("s_waitcnt vmcnt(0)" ::: "memory");
    __syncthreads();

    float cr[2][4] = {};                 // cell state [jjhi][r]
    unsigned tgt = 1;                    // monotonic step id (flag value)
    unsigned* myflags = &flags[ng * 32];

    auto step = [&](auto HASXC,
                    const unsigned* __restrict__ hb,    // ng-offset tiled h src
                    const float (&bj)[2][4],
                    unsigned* __restrict__ hdst)        // full tiled base
    {
        constexpr bool HASX = decltype(HASXC)::value;
        f32x4 acc[2][4] = {};            // [fmL][fg]
        u32x4 pd[8][4];

        // Issue ALL 32 h loads now (asm: cannot be sunk).
        #pragma unroll
        for (int i = 0; i < 8; ++i) {
            const int ch = q + 2 * i;
            ld2g_sys(hb + (2 * ch + tsub) * 1024 + rowcol0, pd[i][0], pd[i][1]);
            ld2g_sys(hb + (2 * ch + tsub) * 1024 + rowcol1, pd[i][2], pd[i][3]);
        }

        // x chunk FIRST: x regs already complete, compute while h flies.
        if constexpr (HASX) {
            WAITV(32);
            bf16x8 bh[4], bl[4];
            if (q == 0) {
                #pragma unroll
                for (int fg = 0; fg < 4; ++fg) {
                    const int bi = ((16 * 4 + rs) * 64 + fg * 16 + c15) * 8;
                    bh[fg] = *(const bf16x8*)&BhS[bi];
                    bl[fg] = *(const bf16x8*)&BlS[bi];
                }
            } else {
                #pragma unroll
                for (int fg = 0; fg < 4; ++fg) { bh[fg] = tbh[fg]; bl[fg] = tbl[fg]; }
            }
            bf16x8 ah0, al0, ah1, al1;
            mkfrag(xpend[0], xpend[1], ah0, al0);
            mkfrag(xpend[2], xpend[3], ah1, al1);
            #pragma unroll
            for (int fg = 0; fg < 4; ++fg) {
                acc[0][fg] = __builtin_amdgcn_mfma_f32_16x16x32_bf16(ah0, bh[fg], acc[0][fg], 0, 0, 0);
                acc[0][fg] = __builtin_amdgcn_mfma_f32_16x16x32_bf16(ah0, bl[fg], acc[0][fg], 0, 0, 0);
                acc[0][fg] = __builtin_amdgcn_mfma_f32_16x16x32_bf16(al0, bh[fg], acc[0][fg], 0, 0, 0);
                acc[1][fg] = __builtin_amdgcn_mfma_f32_16x16x32_bf16(ah1, bh[fg], acc[1][fg], 0, 0, 0);
                acc[1][fg] = __builtin_amdgcn_mfma_f32_16x16x32_bf16(ah1, bl[fg], acc[1][fg], 0, 0, 0);
                acc[1][fg] = __builtin_amdgcn_mfma_f32_16x16x32_bf16(al1, bh[fg], acc[1][fg], 0, 0, 0);
            }
        }

        // K-loop: counted vmcnt ladder releases one chunk at a time.
        #pragma unroll
        for (int i = 0; i < 8; ++i) {
            if      (i == 0) WAITV(28);
            else if (i == 1) WAITV(24);
            else if (i == 2) WAITV(20);
            else if (i == 3) WAITV(16);
            else if (i == 4) WAITV(12);
            else if (i == 5) WAITV(8);
            else if (i == 6) WAITV(4);
            else             WAITV(0);

            const int ch = q + 2 * i;
            bf16x8 bh[4], bl[4];
            #pragma unroll
            for (int fg = 0; fg < 4; ++fg) {
                const int bi = ((ch * 4 + rs) * 64 + fg * 16 + c15) * 8;
                bh[fg] = *(const bf16x8*)&BhS[bi];
                bl[fg] = *(const bf16x8*)&BlS[bi];
            }
            bf16x8 ah0, al0, ah1, al1;
            mkfrag(pd[i][0], pd[i][1], ah0, al0);
            mkfrag(pd[i][2], pd[i][3], ah1, al1);
            #pragma unroll
            for (int fg = 0; fg < 4; ++fg) {
                acc[0][fg] = __builtin_amdgcn_mfma_f32_16x16x32_bf16(ah0, bh[fg], acc[0][fg], 0, 0, 0);
                acc[0][fg] = __builtin_amdgcn_mfma_f32_16x16x32_bf16(ah0, bl[fg], acc[0][fg], 0, 0, 0);
                acc[0][fg] = __builtin_amdgcn_mfma_f32_16x16x32_bf16(al0, bh[fg], acc[0][fg], 0, 0, 0);
                acc[1][fg] = __builtin_amdgcn_mfma_f32_16x16x32_bf16(ah1, bh[fg], acc[1][fg], 0, 0, 0);
                acc[1][fg] = __builtin_amdgcn_mfma_f32_16x16x32_bf16(ah1, bl[fg], acc[1][fg], 0, 0, 0);
                acc[1][fg] = __builtin_amdgcn_mfma_f32_16x16x32_bf16(al1, bh[fg], acc[1][fg], 0, 0, 0);
            }
        }

        // Partner reduction: wave w keeps fm = w (static acc indexing only).
        f32x4 keep[4], give[4];
        if (q == 0) {
            #pragma unroll
            for (int fg = 0; fg < 4; ++fg) { keep[fg] = acc[0][fg]; give[fg] = acc[1][fg]; }
        } else {
            #pragma unroll
            for (int fg = 0; fg < 4; ++fg) { keep[fg] = acc[1][fg]; give[fg] = acc[0][fg]; }
        }
        float* myslot = &red[w * 1280 + lane * 20];
        #pragma unroll
        for (int fg = 0; fg < 4; ++fg) *(f32x4*)&myslot[fg * 4] = give[fg];
        __syncthreads();
        const float* ps = &red[(w ^ 1) * 1280 + lane * 20];
        #pragma unroll
        for (int fg = 0; fg < 4; ++fg) keep[fg] += *(const f32x4*)&ps[fg * 4];
        // (no barrier here: red is next written after ngbar's s_barrier)

        // Epilogue: gates + DIRECT scattered sc0/sc1 stores (32B segments;
        // stores begin issuing mid-epilogue -> earlier drain).
        unsigned* dbase = hdst + (size_t)(ng * 32 + jt) * 1024;
        #pragma unroll
        for (int r = 0; r < 4; ++r) {
            float v0 = keep[0][r], v1 = keep[1][r];
            float v2 = keep[2][r], v3 = keep[3][r];
            float u0 = __shfl_xor(v0, 8, 64);
            float u1 = __shfl_xor(v1, 8, 64);
            float u2 = __shfl_xor(v2, 8, 64);
            float u3 = __shfl_xor(v3, 8, 64);
            if (pl == 0) {
                const int n = w * 16 + (lane >> 4) * 4 + r;
                unsigned* d0 = dbase + n * 16 + (lane & 7);
                {
                    float gi = v0 + bj[0][0], gf = u0 + bj[0][1];
                    float gg = v1 + bj[0][2], go = u1 + bj[0][3];
                    float cn = sigmf(gf) * cr[0][r] + sigmf(gi) * tanh_fast(gg);
                    float hn = sigmf(go) * tanh_fast(cn);
                    cr[0][r] = cn;
                    st_sys(d0, packsplit(hn));
                }
                {
                    float gi = v2 + bj[1][0], gf = u2 + bj[1][1];
                    float gg = v3 + bj[1][2], go = u3 + bj[1][3];
                    float cn = sigmf(gf) * cr[1][r] + sigmf(gi) * tanh_fast(gg);
                    float hn = sigmf(go) * tanh_fast(cn);
                    cr[1][r] = cn;
                    st_sys(d0 + 8, packsplit(hn));
                }
            }
        }
    };

    auto ngbar = [&]() {
        // Drain own stores to MALL, block barrier (all 4 waves drained),
        // publish, then every wave polls independently (no relay, no fence).
        asm volatile("s_waitcnt vmcnt(0) lgkmcnt(0)" ::: "memory");
        asm volatile("s_barrier" ::: "memory");
        if (tid == 0)
            __hip_atomic_store(&myflags[jt], tgt,
                               __ATOMIC_RELAXED, __HIP_MEMORY_SCOPE_AGENT);
        for (;;) {
            unsigned v = __hip_atomic_load(&myflags[lane & 31],
                                           __ATOMIC_RELAXED, __HIP_MEMORY_SCOPE_AGENT);
            if (__all(v >= tgt)) break;
            __builtin_amdgcn_s_sleep(1);
        }
        __builtin_amdgcn_sched_barrier(0);   // pin subsequent h loads after poll
        tgt += 1;
    };

    // ---- encoder: 168 steps (even count -> h_enc lands in slot 0) ----
    for (int t = 0; t < TD; ++t) {
        step(icb<true>{},
             hp + (size_t)(t & 1) * NH + ng * 32768,
             bje,
             hp + (size_t)((t + 1) & 1) * NH);
        if (t + 1 < TD) loadX(t + 1);    // overlaps the drain + poll
        ngbar();
    }

    // ---- swap in decoder weights ----
    stageB(WdH, WdL, slabD, NCHD);
    __syncthreads();
    #pragma unroll
    for (int jj = 0; jj < 2; ++jj)
        #pragma unroll
        for (int r = 0; r < 4; ++r) cr[jj][r] = 0.f;

    // ---- decoder: 24 steps, outputs land in hs slots ----
    for (int s = 0; s < DSTEPS; ++s) {
        const unsigned* hb = ((s == 0) ? hp : hs + (size_t)(s - 1) * NH) + ng * 32768;
        step(icb<false>{}, hb, bjd, hs + (size_t)s * NH);
        ngbar();
    }
}

// ---------------------------------------------------------------------------
// Dense head over TILED hs: out[n][o][t] = sum_k unpack(hs) * Wd + bd.
// (Separate dispatch: kernel boundary provides system coherence for hs.)
// ---------------------------------------------------------------------------
__global__ __launch_bounds__(256)
void dense_kernel(const unsigned* __restrict__ hsP,
                  const float* __restrict__ Wd,
                  const float* __restrict__ bd,
                  float* __restrict__ out)
{
    const int t  = blockIdx.y;
    const int gx = blockIdx.x;          // n-group (n0 = gx*64)
    const int tid = threadIdx.x;
    const int to  = tid & 15;
    const int tn  = tid >> 4;

    __shared__ __align__(16) float aT[32 * 68];
    __shared__ __align__(16) float wT[32 * 68];

    float acc[4][4] = {};

    for (int ch = 0; ch < HD / 32; ++ch) {
        const int k0 = ch * 32;
        __syncthreads();
        #pragma unroll
        for (int i = 0; i < 8; ++i) {
            int e  = tid + i * 256;
            int kk = e & 31;
            int nl = e >> 5;
            int k  = k0 + kk;
            unsigned v = hsP[(size_t)t * (NB * HD)
                             + (size_t)(gx * 32 + (k >> 4)) * 1024 + nl * 16 + (k & 15)];
            aT[kk * 68 + nl] = bf2f((unsigned short)(v >> 16)) + bf2f((unsigned short)(v & 0xffffu));
            wT[kk * 68 + nl] = Wd[((size_t)t * OUTC + nl) * HD + k];
        }
        __syncthreads();
        #pragma unroll
        for (int kk = 0; kk < 32; ++kk) {
            float4 a = *reinterpret_cast<const float4*>(&aT[kk * 68 + tn * 4]);
            float4 wv = *reinterpret_cast<const float4*>(&wT[kk * 68 + to * 4]);
            acc[0][0] += a.x * wv.x; acc[0][1] += a.x * wv.y; acc[0][2] += a.x * wv.z; acc[0][3] += a.x * wv.w;
            acc[1][0] += a.y * wv.x; acc[1][1] += a.y * wv.y; acc[1][2] += a.y * wv.z; acc[1][3] += a.y * wv.w;
            acc[2][0] += a.z * wv.x; acc[2][1] += a.z * wv.y; acc[2][2] += a.z * wv.z; acc[2][3] += a.z * wv.w;
            acc[3][0] += a.w * wv.x; acc[3][1] += a.w * wv.y; acc[3][2] += a.w * wv.z; acc[3][3] += a.w * wv.w;
        }
    }

    #pragma unroll
    for (int i = 0; i < 4; ++i)
        #pragma unroll
        for (int jq = 0; jq < 4; ++jq) {
            int n = gx * 64 + tn * 4 + i;
            int o = to * 4 + jq;
            out[((size_t)n * OUTC + o) * DSTEPS + t] = acc[i][jq] + bd[t * OUTC + o];
        }
}

// ---------------------------------------------------------------------------
extern "C" void kernel_launch(void* const* d_in, const int* in_sizes, int n_in,
                              void* d_out, int out_size, void* d_ws, size_t ws_size,
                              hipStream_t stream) {
    const float* x       = (const float*)d_in[0];
    const float* W_ih_e  = (const float*)d_in[1];
    const float* W_hh_e  = (const float*)d_in[2];
    const float* b_e     = (const float*)d_in[3];
    const float* W_hh_d  = (const float*)d_in[4];
    const float* b_d     = (const float*)d_in[5];
    const float* W_dense = (const float*)d_in[6];
    const float* b_dense = (const float*)d_in[7];
    float* out = (float*)d_out;

    const size_t NH = (size_t)NB * HD;   // 262144 u32 elems

    char* pws = (char*)d_ws;
    auto alloc = [&](size_t bytes) { char* q = pws; pws += (bytes + 255) & ~(size_t)255; return q; };
    unsigned short* WeH = (unsigned short*)alloc((size_t)GATES * KWE * 2);
    unsigned short* WeL = (unsigned short*)alloc((size_t)GATES * KWE * 2);
    unsigned short* WdH = (unsigned short*)alloc((size_t)GATES * HD * 2);
    unsigned short* WdL = (unsigned short*)alloc((size_t)GATES * HD * 2);
    unsigned*       xTl = (unsigned*)alloc((size_t)TD * NB * CD * 4);
    unsigned*       hp  = (unsigned*)alloc(2 * NH * 4);
    unsigned*       hs  = (unsigned*)alloc((size_t)DSTEPS * NH * 4);
    unsigned*       flg = (unsigned*)alloc(8 * 32 * sizeof(unsigned));

    // Prep (every call; deterministic)
    prep_wfrag<<<dim3(32, NCHE), dim3(256), 0, stream>>>(W_hh_e, W_ih_e, WeH, WeL, NCHE);
    prep_wfrag<<<dim3(32, NCHD), dim3(256), 0, stream>>>(W_hh_d, W_hh_d, WdH, WdL, NCHD);
    prep_xT<<<dim3(NB), dim3(256), 0, stream>>>(x, xTl);

    (void)hipMemsetAsync(hp, 0, NH * 4, stream);                 // slot 0 = zeros
    (void)hipMemsetAsync(flg, 0, 8 * 32 * sizeof(unsigned), stream);

    lstm_persist<<<dim3(256), dim3(256), 0, stream>>>(
        WeH, WeL, WdH, WdL, xTl, b_e, b_d, hp, hs, flg);

    dense_kernel<<<dim3(NB / 64, DSTEPS), dim3(256), 0, stream>>>(
        hs, W_dense, b_dense, out);
}

// Round 16
// 1166.453 us; speedup vs baseline: 4.1989x; 1.4291x over previous
//
#include <hip/hip_runtime.h>
#include <math.h>
#include <type_traits>

// Problem constants
#define NB 512     // batch
#define HD 512     // hidden
#define CD 64      // in channels
#define TD 168     // encode length
#define DSTEPS 24  // decoder steps
#define OUTC 64    // out channels
#define GATES 2048 // 4*HD
#define KWE (HD + CD)   // encoder K = 576
#define NCHE 18         // encoder K chunks (32 each)
#define NCHD 16         // decoder K chunks
#define NBLDS 17        // B chunks in LDS (encoder chunk 17 in regs on q=1 waves)

typedef short bf16x8 __attribute__((ext_vector_type(8)));
typedef float f32x4 __attribute__((ext_vector_type(4)));
typedef unsigned u32x4 __attribute__((ext_vector_type(4)));

template<bool B> using icb = std::integral_constant<bool, B>;

// Counted wait + scheduler fence (rule #18: hipcc hoists reg-only MFMA past
// inline-asm waitcnt; sched_barrier(0) right after is the required fence).
#define WAITV(N) do { asm volatile("s_waitcnt vmcnt(" #N ")" ::: "memory"); \
                      __builtin_amdgcn_sched_barrier(0); } while (0)

// Fast gate nonlinearities via v_exp_f32 (2^x) + v_rcp_f32 (~1 ulp each —
// negligible vs the bf16x3 path's 2.4e-4 absmax). Saturation is exact.
__device__ __forceinline__ float rcpf(float x) { return __builtin_amdgcn_rcpf(x); }
__device__ __forceinline__ float sigmf(float x) {
    return rcpf(1.0f + __builtin_amdgcn_exp2f(-1.442695040888963f * x));
}
__device__ __forceinline__ float tanh_fast(float x) {
    return 1.0f - 2.0f * rcpf(1.0f + __builtin_amdgcn_exp2f(2.885390081777926f * x));
}

__device__ __forceinline__ float bf2f(unsigned short h) {
    return __uint_as_float(((unsigned)h) << 16);
}
__device__ __forceinline__ unsigned short f2bf(float x) {  // round-to-nearest-even
    unsigned u = __float_as_uint(x);
    return (unsigned short)((u + 0x7fffu + ((u >> 16) & 1u)) >> 16);
}
__device__ __forceinline__ unsigned packsplit(float v) {   // bf16 hi|lo packed
    unsigned short hi = f2bf(v);
    unsigned short lo = f2bf(v - bf2f(hi));
    return ((unsigned)hi << 16) | (unsigned)lo;
}

// Build hi/lo bf16x8 fragments from 8 packed (hi<<16|lo) words via v_perm.
__device__ __forceinline__ void mkfrag(u32x4 a, u32x4 b, bf16x8& hi, bf16x8& lo) {
    u32x4 h, l;
    h.x = __builtin_amdgcn_perm(a.y, a.x, 0x07060302u);
    h.y = __builtin_amdgcn_perm(a.w, a.z, 0x07060302u);
    h.z = __builtin_amdgcn_perm(b.y, b.x, 0x07060302u);
    h.w = __builtin_amdgcn_perm(b.w, b.z, 0x07060302u);
    l.x = __builtin_amdgcn_perm(a.y, a.x, 0x05040100u);
    l.y = __builtin_amdgcn_perm(a.w, a.z, 0x05040100u);
    l.z = __builtin_amdgcn_perm(b.y, b.x, 0x05040100u);
    l.w = __builtin_amdgcn_perm(b.w, b.z, 0x05040100u);
    hi = *(bf16x8*)&h;
    lo = *(bf16x8*)&l;
}

// h loads: sc0 ONLY — bypass stale L1, hit the SHARED per-XCD L2. All blocks
// of an n-group (bid%8 == ng) sit on one XCD under round-robin dispatch, and
// CDNA's write-through L1 puts plain h stores in that same L2, so sc0 reads
// are coherent after the MALL-scope flag handshake orders them.
__device__ __forceinline__ void ld2g_l2(const unsigned* p, u32x4& a, u32x4& b) {
    asm volatile("global_load_dwordx4 %0, %2, off sc0\n\t"
                 "global_load_dwordx4 %1, %2, off offset:16 sc0"
                 : "=&v"(a), "=&v"(b) : "v"(p) : "memory");
}
// x loads: plain cached (x is read-only; no staleness possible).
__device__ __forceinline__ void ld2g_x(const unsigned* p, u32x4& a, u32x4& b) {
    asm volatile("global_load_dwordx4 %0, %2, off\n\t"
                 "global_load_dwordx4 %1, %2, off offset:16"
                 : "=&v"(a), "=&v"(b) : "v"(p));
}
// Epilogue h store: PLAIN (write-through L1 -> shared XCD L2; no MALL trip).
__device__ __forceinline__ void st_l2(unsigned* p, unsigned v) {
    asm volatile("global_store_dword %0, %1, off"
                 :: "v"(p), "v"(v) : "memory");
}

// ---------------------------------------------------------------------------
// Weight prep: bf16 hi/lo planes, permuted + fragment-ready.
// Elem [(ch*4+ks)*64 + gc][m] holds source row gate*HD + jt*16 + jj at
// k = ch*32 + ks*8 + m, with gate=(gc>>3)&3, jj=(gc&7)+8*(gc>>5).
// ---------------------------------------------------------------------------
__global__ __launch_bounds__(256)
void prep_wfrag(const float* __restrict__ Whh, const float* __restrict__ Wih,
                unsigned short* __restrict__ Ph, unsigned short* __restrict__ Pl,
                int nch)
{
    const int jt = blockIdx.x, ch = blockIdx.y;
    const int ks = threadIdx.x >> 6, gc = threadIdx.x & 63;
    const int gate = (gc >> 3) & 3;
    const int jj = (gc & 7) + ((gc >> 5) << 3);
    const int srow = gate * HD + jt * 16 + jj;
    const int k0 = ch * 32 + ks * 8;
    const size_t o = (size_t)jt * (64 * nch * 32) + (size_t)((ch * 4 + ks) * 64 + gc) * 8;
    #pragma unroll
    for (int m = 0; m < 8; ++m) {
        int k = k0 + m;
        float v = (k < HD) ? Whh[(size_t)srow * HD + k] : Wih[(size_t)srow * CD + (k - HD)];
        unsigned short hi = f2bf(v);
        Ph[o + m] = hi;
        Pl[o + m] = f2bf(v - bf2f(hi));
    }
}

// ---------------------------------------------------------------------------
// x prep: (N,C,T) f32 -> packed u32, TILED: xT[t][ng][ct][64][16].
// ---------------------------------------------------------------------------
__global__ __launch_bounds__(256)
void prep_xT(const float* __restrict__ x, unsigned* __restrict__ Xt)
{
    __shared__ float tile[CD * TD];
    const int n = blockIdx.x;
    for (int e = threadIdx.x; e < CD * TD; e += 256)
        tile[e] = x[(size_t)n * CD * TD + e];
    __syncthreads();
    for (int e = threadIdx.x; e < CD * TD; e += 256) {
        int t = e >> 6, c = e & 63;
        size_t o = ((size_t)(t * 8 + (n >> 6)) * 4 + (c >> 4)) * 1024 + (n & 63) * 16 + (c & 15);
        Xt[o] = packsplit(tile[c * TD + t]);
    }
}

// ---------------------------------------------------------------------------
// Persistent encoder+decoder. 256 blocks x 256 threads (4 waves), 1 block/CU.
// r15 base with L2-LOCAL h exchange: plain h stores (land in shared XCD L2
// via write-through L1) + sc0 h loads (bypass L1, hit that L2). The agent-
// scope flag handshake (via MALL) orders the exchange. Correctness rides on
// n-group (bid%8) == XCD co-residency; violation -> wrong values (caught by
// absmax), not a hang.
// ---------------------------------------------------------------------------
__global__ __launch_bounds__(256, 1)
void lstm_persist(const unsigned short* __restrict__ WeH, const unsigned short* __restrict__ WeL,
                  const unsigned short* __restrict__ WdH, const unsigned short* __restrict__ WdL,
                  const unsigned* __restrict__ xT,
                  const float* __restrict__ b_e, const float* __restrict__ b_d,
                  unsigned* __restrict__ hp,   // [2][NB*HD] packed, tiled
                  unsigned* __restrict__ hs,   // [DSTEPS][NB*HD] packed, tiled
                  unsigned* __restrict__ flags)
{
    __shared__ __align__(16) unsigned short BhS[NBLDS * 2048];  // 69632 B
    __shared__ __align__(16) unsigned short BlS[NBLDS * 2048];  // 69632 B
    __shared__ __align__(16) float red[4 * 1280];               // 20480 B

    const int tid  = threadIdx.x;
    const int lane = tid & 63;
    const int w    = tid >> 6;          // wave 0..3
    const int p2   = w >> 1;            // fm-pair (rows p2*32..+31)
    const int q    = w & 1;             // chunk parity
    const int jt   = blockIdx.x >> 3;   // 0..31
    const int ng   = blockIdx.x & 7;    // n-group == XCD (round-robin dispatch)

    const int rs    = lane >> 4;        // frag k-slot 0..3
    const int c15   = lane & 15;
    const int pl    = (lane >> 3) & 1;
    const int jbase = jt * 16 + (lane & 7);
    const int rowcol0 = (p2 * 32 + c15) * 16 + (rs & 1) * 8;        // fmL=0
    const int rowcol1 = (p2 * 32 + 16 + c15) * 16 + (rs & 1) * 8;   // fmL=1
    const int tsub    = rs >> 1;        // which of the chunk's 2 tiles

    const size_t slabE = (size_t)jt * (64 * KWE);
    const size_t slabD = (size_t)jt * (64 * HD);
    const size_t NH    = (size_t)NB * HD;   // u32 elems per h buffer

    // Biases
    float bje[2][4], bjd[2][4];
    #pragma unroll
    for (int g = 0; g < 4; ++g) {
        bje[0][g] = b_e[g * HD + jbase];
        bje[1][g] = b_e[g * HD + jbase + 8];
        bjd[0][g] = b_d[g * HD + jbase];
        bjd[1][g] = b_d[g * HD + jbase + 8];
    }

    auto stageB = [&](const unsigned short* PH, const unsigned short* PL,
                      size_t slab, int nchunks) {
        for (int e = tid; e < nchunks * 256; e += 256) {
            *(bf16x8*)&BhS[(size_t)e * 8] = *(const bf16x8*)&PH[slab + (size_t)e * 8];
            *(bf16x8*)&BlS[(size_t)e * 8] = *(const bf16x8*)&PL[slab + (size_t)e * 8];
        }
    };
    // Encoder tail B chunk (17) in regs on q==1 waves.
    bf16x8 tbh[4], tbl[4];
    if (q == 1) {
        #pragma unroll
        for (int fg = 0; fg < 4; ++fg) {
            size_t o = slabE + (size_t)((17 * 4 + rs) * 64 + fg * 16 + c15) * 8;
            tbh[fg] = *(const bf16x8*)&WeH[o];
            tbl[fg] = *(const bf16x8*)&WeL[o];
        }
    }
    stageB(WeH, WeL, slabE, NBLDS);

    // x prefetch regs (chunk 16 for q=0, 17 for q=1)
    u32x4 xpend[4];
    auto loadX = [&](int t) {
        const unsigned* xb = xT + (size_t)((t * 8 + ng) * 4) * 1024;
        ld2g_x(xb + (q * 2 + tsub) * 1024 + rowcol0, xpend[0], xpend[1]);
        ld2g_x(xb + (q * 2 + tsub) * 1024 + rowcol1, xpend[2], xpend[3]);
    };
    loadX(0);
    asm volatile("s_waitcnt vmcnt(0)" ::: "memory");
    __syncthreads();

    float cr[2][4] = {};                 // cell state [jjhi][r]
    unsigned tgt = 1;                    // monotonic step id (flag value)
    unsigned* myflags = &flags[ng * 32];

    auto step = [&](auto HASXC,
                    const unsigned* __restrict__ hb,    // ng-offset tiled h src
                    const float (&bj)[2][4],
                    unsigned* __restrict__ hdst)        // full tiled base
    {
        constexpr bool HASX = decltype(HASXC)::value;
        f32x4 acc[2][4] = {};            // [fmL][fg]
        u32x4 pd[8][4];

        // Issue ALL 32 h loads now (asm: cannot be sunk). L2-local.
        #pragma unroll
        for (int i = 0; i < 8; ++i) {
            const int ch = q + 2 * i;
            ld2g_l2(hb + (2 * ch + tsub) * 1024 + rowcol0, pd[i][0], pd[i][1]);
            ld2g_l2(hb + (2 * ch + tsub) * 1024 + rowcol1, pd[i][2], pd[i][3]);
        }

        // x chunk FIRST: x regs already complete, compute while h flies.
        if constexpr (HASX) {
            WAITV(32);
            bf16x8 bh[4], bl[4];
            if (q == 0) {
                #pragma unroll
                for (int fg = 0; fg < 4; ++fg) {
                    const int bi = ((16 * 4 + rs) * 64 + fg * 16 + c15) * 8;
                    bh[fg] = *(const bf16x8*)&BhS[bi];
                    bl[fg] = *(const bf16x8*)&BlS[bi];
                }
            } else {
                #pragma unroll
                for (int fg = 0; fg < 4; ++fg) { bh[fg] = tbh[fg]; bl[fg] = tbl[fg]; }
            }
            bf16x8 ah0, al0, ah1, al1;
            mkfrag(xpend[0], xpend[1], ah0, al0);
            mkfrag(xpend[2], xpend[3], ah1, al1);
            #pragma unroll
            for (int fg = 0; fg < 4; ++fg) {
                acc[0][fg] = __builtin_amdgcn_mfma_f32_16x16x32_bf16(ah0, bh[fg], acc[0][fg], 0, 0, 0);
                acc[0][fg] = __builtin_amdgcn_mfma_f32_16x16x32_bf16(ah0, bl[fg], acc[0][fg], 0, 0, 0);
                acc[0][fg] = __builtin_amdgcn_mfma_f32_16x16x32_bf16(al0, bh[fg], acc[0][fg], 0, 0, 0);
                acc[1][fg] = __builtin_amdgcn_mfma_f32_16x16x32_bf16(ah1, bh[fg], acc[1][fg], 0, 0, 0);
                acc[1][fg] = __builtin_amdgcn_mfma_f32_16x16x32_bf16(ah1, bl[fg], acc[1][fg], 0, 0, 0);
                acc[1][fg] = __builtin_amdgcn_mfma_f32_16x16x32_bf16(al1, bh[fg], acc[1][fg], 0, 0, 0);
            }
        }

        // K-loop: counted vmcnt ladder releases one chunk at a time.
        #pragma unroll
        for (int i = 0; i < 8; ++i) {
            if      (i == 0) WAITV(28);
            else if (i == 1) WAITV(24);
            else if (i == 2) WAITV(20);
            else if (i == 3) WAITV(16);
            else if (i == 4) WAITV(12);
            else if (i == 5) WAITV(8);
            else if (i == 6) WAITV(4);
            else             WAITV(0);

            const int ch = q + 2 * i;
            bf16x8 bh[4], bl[4];
            #pragma unroll
            for (int fg = 0; fg < 4; ++fg) {
                const int bi = ((ch * 4 + rs) * 64 + fg * 16 + c15) * 8;
                bh[fg] = *(const bf16x8*)&BhS[bi];
                bl[fg] = *(const bf16x8*)&BlS[bi];
            }
            bf16x8 ah0, al0, ah1, al1;
            mkfrag(pd[i][0], pd[i][1], ah0, al0);
            mkfrag(pd[i][2], pd[i][3], ah1, al1);
            #pragma unroll
            for (int fg = 0; fg < 4; ++fg) {
                acc[0][fg] = __builtin_amdgcn_mfma_f32_16x16x32_bf16(ah0, bh[fg], acc[0][fg], 0, 0, 0);
                acc[0][fg] = __builtin_amdgcn_mfma_f32_16x16x32_bf16(ah0, bl[fg], acc[0][fg], 0, 0, 0);
                acc[0][fg] = __builtin_amdgcn_mfma_f32_16x16x32_bf16(al0, bh[fg], acc[0][fg], 0, 0, 0);
                acc[1][fg] = __builtin_amdgcn_mfma_f32_16x16x32_bf16(ah1, bh[fg], acc[1][fg], 0, 0, 0);
                acc[1][fg] = __builtin_amdgcn_mfma_f32_16x16x32_bf16(ah1, bl[fg], acc[1][fg], 0, 0, 0);
                acc[1][fg] = __builtin_amdgcn_mfma_f32_16x16x32_bf16(al1, bh[fg], acc[1][fg], 0, 0, 0);
            }
        }

        // Partner reduction: wave w keeps fm = w (static acc indexing only).
        f32x4 keep[4], give[4];
        if (q == 0) {
            #pragma unroll
            for (int fg = 0; fg < 4; ++fg) { keep[fg] = acc[0][fg]; give[fg] = acc[1][fg]; }
        } else {
            #pragma unroll
            for (int fg = 0; fg < 4; ++fg) { keep[fg] = acc[1][fg]; give[fg] = acc[0][fg]; }
        }
        float* myslot = &red[w * 1280 + lane * 20];
        #pragma unroll
        for (int fg = 0; fg < 4; ++fg) *(f32x4*)&myslot[fg * 4] = give[fg];
        __syncthreads();
        const float* ps = &red[(w ^ 1) * 1280 + lane * 20];
        #pragma unroll
        for (int fg = 0; fg < 4; ++fg) keep[fg] += *(const f32x4*)&ps[fg * 4];
        // (no barrier here: red is next written after ngbar's s_barrier)

        // Epilogue: gates + direct scattered PLAIN stores (land in shared L2).
        unsigned* dbase = hdst + (size_t)(ng * 32 + jt) * 1024;
        #pragma unroll
        for (int r = 0; r < 4; ++r) {
            float v0 = keep[0][r], v1 = keep[1][r];
            float v2 = keep[2][r], v3 = keep[3][r];
            float u0 = __shfl_xor(v0, 8, 64);
            float u1 = __shfl_xor(v1, 8, 64);
            float u2 = __shfl_xor(v2, 8, 64);
            float u3 = __shfl_xor(v3, 8, 64);
            if (pl == 0) {
                const int n = w * 16 + (lane >> 4) * 4 + r;
                unsigned* d0 = dbase + n * 16 + (lane & 7);
                {
                    float gi = v0 + bj[0][0], gf = u0 + bj[0][1];
                    float gg = v1 + bj[0][2], go = u1 + bj[0][3];
                    float cn = sigmf(gf) * cr[0][r] + sigmf(gi) * tanh_fast(gg);
                    float hn = sigmf(go) * tanh_fast(cn);
                    cr[0][r] = cn;
                    st_l2(d0, packsplit(hn));
                }
                {
                    float gi = v2 + bj[1][0], gf = u2 + bj[1][1];
                    float gg = v3 + bj[1][2], go = u3 + bj[1][3];
                    float cn = sigmf(gf) * cr[1][r] + sigmf(gi) * tanh_fast(gg);
                    float hn = sigmf(go) * tanh_fast(cn);
                    cr[1][r] = cn;
                    st_l2(d0 + 8, packsplit(hn));
                }
            }
        }
    };

    auto ngbar = [&]() {
        // Drain own stores into the shared L2, block barrier (all 4 waves
        // drained), publish via MALL, then every wave polls independently.
        asm volatile("s_waitcnt vmcnt(0) lgkmcnt(0)" ::: "memory");
        asm volatile("s_barrier" ::: "memory");
        if (tid == 0)
            __hip_atomic_store(&myflags[jt], tgt,
                               __ATOMIC_RELAXED, __HIP_MEMORY_SCOPE_AGENT);
        for (;;) {
            unsigned v = __hip_atomic_load(&myflags[lane & 31],
                                           __ATOMIC_RELAXED, __HIP_MEMORY_SCOPE_AGENT);
            if (__all(v >= tgt)) break;
            __builtin_amdgcn_s_sleep(1);
        }
        __builtin_amdgcn_sched_barrier(0);   // pin subsequent h loads after poll
        tgt += 1;
    };

    // ---- encoder: 168 steps (even count -> h_enc lands in slot 0) ----
    for (int t = 0; t < TD; ++t) {
        step(icb<true>{},
             hp + (size_t)(t & 1) * NH + ng * 32768,
             bje,
             hp + (size_t)((t + 1) & 1) * NH);
        if (t + 1 < TD) loadX(t + 1);    // overlaps the drain + poll
        ngbar();
    }

    // ---- swap in decoder weights ----
    stageB(WdH, WdL, slabD, NCHD);
    __syncthreads();
    #pragma unroll
    for (int jj = 0; jj < 2; ++jj)
        #pragma unroll
        for (int r = 0; r < 4; ++r) cr[jj][r] = 0.f;

    // ---- decoder: 24 steps, outputs land in hs slots ----
    for (int s = 0; s < DSTEPS; ++s) {
        const unsigned* hb = ((s == 0) ? hp : hs + (size_t)(s - 1) * NH) + ng * 32768;
        step(icb<false>{}, hb, bjd, hs + (size_t)s * NH);
        ngbar();
    }
}

// ---------------------------------------------------------------------------
// Dense head over TILED hs: out[n][o][t] = sum_k unpack(hs) * Wd + bd.
// (Separate dispatch: kernel-boundary cache writeback makes hs visible.)
// ---------------------------------------------------------------------------
__global__ __launch_bounds__(256)
void dense_kernel(const unsigned* __restrict__ hsP,
                  const float* __restrict__ Wd,
                  const float* __restrict__ bd,
                  float* __restrict__ out)
{
    const int t  = blockIdx.y;
    const int gx = blockIdx.x;          // n-group (n0 = gx*64)
    const int tid = threadIdx.x;
    const int to  = tid & 15;
    const int tn  = tid >> 4;

    __shared__ __align__(16) float aT[32 * 68];
    __shared__ __align__(16) float wT[32 * 68];

    float acc[4][4] = {};

    for (int ch = 0; ch < HD / 32; ++ch) {
        const int k0 = ch * 32;
        __syncthreads();
        #pragma unroll
        for (int i = 0; i < 8; ++i) {
            int e  = tid + i * 256;
            int kk = e & 31;
            int nl = e >> 5;
            int k  = k0 + kk;
            unsigned v = hsP[(size_t)t * (NB * HD)
                             + (size_t)(gx * 32 + (k >> 4)) * 1024 + nl * 16 + (k & 15)];
            aT[kk * 68 + nl] = bf2f((unsigned short)(v >> 16)) + bf2f((unsigned short)(v & 0xffffu));
            wT[kk * 68 + nl] = Wd[((size_t)t * OUTC + nl) * HD + k];
        }
        __syncthreads();
        #pragma unroll
        for (int kk = 0; kk < 32; ++kk) {
            float4 a = *reinterpret_cast<const float4*>(&aT[kk * 68 + tn * 4]);
            float4 wv = *reinterpret_cast<const float4*>(&wT[kk * 68 + to * 4]);
            acc[0][0] += a.x * wv.x; acc[0][1] += a.x * wv.y; acc[0][2] += a.x * wv.z; acc[0][3] += a.x * wv.w;
            acc[1][0] += a.y * wv.x; acc[1][1] += a.y * wv.y; acc[1][2] += a.y * wv.z; acc[1][3] += a.y * wv.w;
            acc[2][0] += a.z * wv.x; acc[2][1] += a.z * wv.y; acc[2][2] += a.z * wv.z; acc[2][3] += a.z * wv.w;
            acc[3][0] += a.w * wv.x; acc[3][1] += a.w * wv.y; acc[3][2] += a.w * wv.z; acc[3][3] += a.w * wv.w;
        }
    }

    #pragma unroll
    for (int i = 0; i < 4; ++i)
        #pragma unroll
        for (int jq = 0; jq < 4; ++jq) {
            int n = gx * 64 + tn * 4 + i;
            int o = to * 4 + jq;
            out[((size_t)n * OUTC + o) * DSTEPS + t] = acc[i][jq] + bd[t * OUTC + o];
        }
}

// ---------------------------------------------------------------------------
extern "C" void kernel_launch(void* const* d_in, const int* in_sizes, int n_in,
                              void* d_out, int out_size, void* d_ws, size_t ws_size,
                              hipStream_t stream) {
    const float* x       = (const float*)d_in[0];
    const float* W_ih_e  = (const float*)d_in[1];
    const float* W_hh_e  = (const float*)d_in[2];
    const float* b_e     = (const float*)d_in[3];
    const float* W_hh_d  = (const float*)d_in[4];
    const float* b_d     = (const float*)d_in[5];
    const float* W_dense = (const float*)d_in[6];
    const float* b_dense = (const float*)d_in[7];
    float* out = (float*)d_out;

    const size_t NH = (size_t)NB * HD;   // 262144 u32 elems

    char* pws = (char*)d_ws;
    auto alloc = [&](size_t bytes) { char* q = pws; pws += (bytes + 255) & ~(size_t)255; return q; };
    unsigned short* WeH = (unsigned short*)alloc((size_t)GATES * KWE * 2);
    unsigned short* WeL = (unsigned short*)alloc((size_t)GATES * KWE * 2);
    unsigned short* WdH = (unsigned short*)alloc((size_t)GATES * HD * 2);
    unsigned short* WdL = (unsigned short*)alloc((size_t)GATES * HD * 2);
    unsigned*       xTl = (unsigned*)alloc((size_t)TD * NB * CD * 4);
    unsigned*       hp  = (unsigned*)alloc(2 * NH * 4);
    unsigned*       hs  = (unsigned*)alloc((size_t)DSTEPS * NH * 4);
    unsigned*       flg = (unsigned*)alloc(8 * 32 * sizeof(unsigned));

    // Prep (every call; deterministic)
    prep_wfrag<<<dim3(32, NCHE), dim3(256), 0, stream>>>(W_hh_e, W_ih_e, WeH, WeL, NCHE);
    prep_wfrag<<<dim3(32, NCHD), dim3(256), 0, stream>>>(W_hh_d, W_hh_d, WdH, WdL, NCHD);
    prep_xT<<<dim3(NB), dim3(256), 0, stream>>>(x, xTl);

    (void)hipMemsetAsync(hp, 0, NH * 4, stream);                 // slot 0 = zeros
    (void)hipMemsetAsync(flg, 0, 8 * 32 * sizeof(unsigned), stream);

    lstm_persist<<<dim3(256), dim3(256), 0, stream>>>(
        WeH, WeL, WdH, WdL, xTl, b_e, b_d, hp, hs, flg);

    dense_kernel<<<dim3(NB / 64, DSTEPS), dim3(256), 0, stream>>>(
        hs, W_dense, b_dense, out);
}